// Round 1
// baseline (359.747 us; speedup 1.0000x reference)
//
#include <hip/hip_runtime.h>
#include <hip/hip_bf16.h>
#include <stdint.h>

#define K_DIM 4096

typedef __attribute__((ext_vector_type(4))) float f32x4;
typedef __attribute__((ext_vector_type(8))) short short8;

#define GLOAD_LDS16(g, l)                                                        \
  __builtin_amdgcn_global_load_lds(                                              \
      (const __attribute__((address_space(1))) void*)(g),                        \
      (__attribute__((address_space(3))) void*)(l), 16, 0, 0)

// ---------------- gamma = mean(|W|): deterministic 2-stage reduction ----------
__global__ void absum_partial(const float* __restrict__ W,
                              float* __restrict__ partials, int n) {
  int tid = blockIdx.x * blockDim.x + threadIdx.x;
  int stride = gridDim.x * blockDim.x;
  const f32x4* W4 = (const f32x4*)W;
  int n4 = n >> 2;
  float s = 0.f;
  for (int i = tid; i < n4; i += stride) {
    f32x4 v = W4[i];
    s += fabsf(v[0]) + fabsf(v[1]) + fabsf(v[2]) + fabsf(v[3]);
  }
#pragma unroll
  for (int off = 32; off > 0; off >>= 1) s += __shfl_down(s, off, 64);
  __shared__ float wsum[4];
  if ((threadIdx.x & 63) == 0) wsum[threadIdx.x >> 6] = s;
  __syncthreads();
  if (threadIdx.x == 0)
    partials[blockIdx.x] = wsum[0] + wsum[1] + wsum[2] + wsum[3];
}

__global__ void gamma_finalize(const float* __restrict__ partials,
                               float* __restrict__ gamma, float inv_n) {
  __shared__ float sm[256];
  int t = threadIdx.x;
  sm[t] = partials[t] + partials[t + 256] + partials[t + 512] + partials[t + 768];
  __syncthreads();
  for (int off = 128; off > 0; off >>= 1) {
    if (t < off) sm[t] += sm[t + off];
    __syncthreads();
  }
  if (t == 0) gamma[0] = sm[0] * inv_n;
}

// ---------------- W -> ternary bf16 (exact {-1,0,1}) --------------------------
__global__ void quantize_w(const float* __restrict__ W,
                           unsigned short* __restrict__ Wq,
                           const float* __restrict__ gamma_p, int n) {
  float g = gamma_p[0];
  float safe = (g == 0.f) ? 1.f : g;
  int tid = blockIdx.x * blockDim.x + threadIdx.x;
  int stride = gridDim.x * blockDim.x;
  const f32x4* W4 = (const f32x4*)W;
  int n4 = n >> 2;
  for (int i = tid; i < n4; i += stride) {
    f32x4 v = W4[i];
    ushort4 q;
    float t0 = rintf(v[0] / safe);
    float t1 = rintf(v[1] / safe);
    float t2 = rintf(v[2] / safe);
    float t3 = rintf(v[3] / safe);
    q.x = (t0 >= 0.5f) ? 0x3F80u : (t0 <= -0.5f ? 0xBF80u : 0u);
    q.y = (t1 >= 0.5f) ? 0x3F80u : (t1 <= -0.5f ? 0xBF80u : 0u);
    q.z = (t2 >= 0.5f) ? 0x3F80u : (t2 <= -0.5f ? 0xBF80u : 0u);
    q.w = (t3 >= 0.5f) ? 0x3F80u : (t3 <= -0.5f ? 0xBF80u : 0u);
    ((ushort4*)Wq)[i] = q;
  }
}

// ---------------- x fp32 -> bf16 (RTN-even) -----------------------------------
__global__ void convert_x(const float* __restrict__ X,
                          unsigned short* __restrict__ Xb, int n) {
  int tid = blockIdx.x * blockDim.x + threadIdx.x;
  int stride = gridDim.x * blockDim.x;
  const f32x4* X4 = (const f32x4*)X;
  int n4 = n >> 2;
  for (int i = tid; i < n4; i += stride) {
    f32x4 v = X4[i];
    ushort4 o;
    unsigned u0 = __float_as_uint(v[0]);
    unsigned u1 = __float_as_uint(v[1]);
    unsigned u2 = __float_as_uint(v[2]);
    unsigned u3 = __float_as_uint(v[3]);
    o.x = (unsigned short)((u0 + 0x7FFFu + ((u0 >> 16) & 1u)) >> 16);
    o.y = (unsigned short)((u1 + 0x7FFFu + ((u1 >> 16) & 1u)) >> 16);
    o.z = (unsigned short)((u2 + 0x7FFFu + ((u2 >> 16) & 1u)) >> 16);
    o.w = (unsigned short)((u3 + 0x7FFFu + ((u3 >> 16) & 1u)) >> 16);
    ((ushort4*)Xb)[i] = o;
  }
}

// ---------------- bf16 GEMM: C[m][n] = gamma * sum_k A[m][k]*B[n][k] ----------
// A: [M][K] bf16 (x), B: [N][K] bf16 (W_q, B^T layout). 128x128 tile, BK=64,
// 256 threads = 4 waves (2x2), each wave 64x64 = 4x4 fragments of 16x16x32.
__global__ void gemm_bt(const unsigned short* __restrict__ A,
                        const unsigned short* __restrict__ Bq,
                        float* __restrict__ C,
                        const float* __restrict__ gamma_p, int M, int N) {
  __shared__ __align__(16) unsigned short As[128 * 64];
  __shared__ __align__(16) unsigned short Bs[128 * 64];

  int ntN = N >> 7;
  int nwg = gridDim.x;
  int bid = blockIdx.x;
  // bijective XCD-aware swizzle (m204 form)
  int q = nwg >> 3, r = nwg & 7;
  int xcd = bid & 7, orig = bid >> 3;
  int swz = (xcd < r ? xcd * (q + 1) : r * (q + 1) + (xcd - r) * q) + orig;
  int tm = swz / ntN, tn = swz % ntN;

  int tid = threadIdx.x;
  int lane = tid & 63;
  int wid = tid >> 6;
  int wr = wid >> 1, wc = wid & 1;
  int lr = lane & 15;            // fragment row (A) / col-row (B)
  int lk = (lane >> 4) << 3;     // k sub-offset {0,8,16,24}

  const char* aG = (const char*)(A + (size_t)tm * 128 * K_DIM);
  const char* bG = (const char*)(Bq + (size_t)tn * 128 * K_DIM);
  char* aL = (char*)As;
  char* bL = (char*)Bs;

  f32x4 acc[4][4];
#pragma unroll
  for (int m = 0; m < 4; ++m)
#pragma unroll
    for (int n = 0; n < 4; ++n) acc[m][n] = (f32x4)(0.f);

  int row_s = tid >> 3;          // staging row within 32-row chunk
  int colb_s = (tid & 7) << 4;   // staging byte-col (0..112)

  for (int k0 = 0; k0 < K_DIM; k0 += 64) {
    const char* aSrc = aG + (size_t)k0 * 2;
    const char* bSrc = bG + (size_t)k0 * 2;
#pragma unroll
    for (int i = 0; i < 4; ++i) {
      int row = i * 32 + row_s;
      GLOAD_LDS16(aSrc + (size_t)row * (K_DIM * 2) + colb_s, aL + i * 4096 + tid * 16);
      GLOAD_LDS16(bSrc + (size_t)row * (K_DIM * 2) + colb_s, bL + i * 4096 + tid * 16);
    }
    __syncthreads();  // drains vmcnt -> LDS tiles ready

#pragma unroll
    for (int kk = 0; kk < 64; kk += 32) {
      short8 af[4], bf_[4];
#pragma unroll
      for (int m = 0; m < 4; ++m)
        af[m] = *(const short8*)&As[(wr * 64 + m * 16 + lr) * 64 + kk + lk];
#pragma unroll
      for (int n = 0; n < 4; ++n)
        bf_[n] = *(const short8*)&Bs[(wc * 64 + n * 16 + lr) * 64 + kk + lk];
#pragma unroll
      for (int m = 0; m < 4; ++m)
#pragma unroll
        for (int n = 0; n < 4; ++n)
          acc[m][n] = __builtin_amdgcn_mfma_f32_16x16x32_bf16(af[m], bf_[n],
                                                              acc[m][n], 0, 0, 0);
    }
    __syncthreads();  // compute done, safe to overwrite LDS
  }

  float g = gamma_p[0];
  int crow = (lane >> 4) << 2;   // C/D: col = lane&15, row = (lane>>4)*4 + reg
  size_t row0 = (size_t)tm * 128 + wr * 64 + crow;
  int col0 = tn * 128 + wc * 64 + lr;
#pragma unroll
  for (int m = 0; m < 4; ++m) {
#pragma unroll
    for (int j = 0; j < 4; ++j) {
      float* cp = C + (row0 + m * 16 + j) * (size_t)N + col0;
#pragma unroll
      for (int n = 0; n < 4; ++n) cp[n * 16] = acc[m][n][j] * g;
    }
  }
}

// ---------------- naive fallback (only if ws too small) -----------------------
__global__ void naive_bitlinear(const float* __restrict__ X,
                                const float* __restrict__ W,
                                float* __restrict__ out,
                                const float* __restrict__ gamma_p, int M, int N) {
  int col = blockIdx.x * blockDim.x + threadIdx.x;
  int row = blockIdx.y;
  if (col >= N || row >= M) return;
  float g = gamma_p[0];
  float safe = (g == 0.f) ? 1.f : g;
  const float* x = X + (size_t)row * K_DIM;
  const float* w = W + (size_t)col * K_DIM;
  float s = 0.f;
  for (int k = 0; k < K_DIM; ++k) {
    float qv = fminf(fmaxf(rintf(w[k] / safe), -1.f), 1.f);
    s += x[k] * qv;
  }
  out[(size_t)row * N + col] = s * g;
}

extern "C" void kernel_launch(void* const* d_in, const int* in_sizes, int n_in,
                              void* d_out, int out_size, void* d_ws,
                              size_t ws_size, hipStream_t stream) {
  const float* x = (const float*)d_in[0];
  const float* w = (const float*)d_in[1];
  float* out = (float*)d_out;
  int xn = in_sizes[0];   // B*S*D_IN = 33554432
  int wn = in_sizes[1];   // D_OUT*D_IN = 16777216
  int M = xn / K_DIM;     // 8192
  int N = wn / K_DIM;     // 4096

  char* ws = (char*)d_ws;
  float* partials = (float*)ws;                       // 1024 floats
  float* gamma = (float*)(ws + 4096);                 // 1 float
  unsigned short* Wq = (unsigned short*)(ws + 8192);  // N*K bf16
  unsigned short* Xb = Wq + (size_t)wn;               // M*K bf16
  size_t need = 8192 + (size_t)wn * 2 + (size_t)xn * 2;

  absum_partial<<<1024, 256, 0, stream>>>(w, partials, wn);
  gamma_finalize<<<1, 256, 0, stream>>>(partials, gamma, 1.0f / (float)wn);

  if (ws_size >= need && (M & 127) == 0 && (N & 127) == 0) {
    quantize_w<<<2048, 256, 0, stream>>>(w, Wq, gamma, wn);
    convert_x<<<2048, 256, 0, stream>>>(x, Xb, xn);
    int nwg = (M >> 7) * (N >> 7);
    gemm_bt<<<nwg, 256, 0, stream>>>(Xb, Wq, out, gamma, M, N);
  } else {
    dim3 grid((N + 255) / 256, M);
    naive_bitlinear<<<grid, 256, 0, stream>>>(x, w, out, gamma, M, N);
  }
}

// Round 2
// 327.992 us; speedup vs baseline: 1.0968x; 1.0968x over previous
//
#include <hip/hip_runtime.h>
#include <hip/hip_bf16.h>
#include <stdint.h>

#define K_DIM 4096
#define NKT   (K_DIM / 32)   // 128 K-tiles of BK=32

typedef __attribute__((ext_vector_type(4))) float f32x4;
typedef __attribute__((ext_vector_type(8))) short short8;

#define GLOAD_LDS16(g, l)                                                        \
  __builtin_amdgcn_global_load_lds(                                              \
      (const __attribute__((address_space(1))) void*)(g),                        \
      (__attribute__((address_space(3))) void*)(l), 16, 0, 0)

// ---------------- gamma = mean(|W|): deterministic 2-stage reduction ----------
__global__ void absum_partial(const float* __restrict__ W,
                              float* __restrict__ partials, int n) {
  int tid = blockIdx.x * blockDim.x + threadIdx.x;
  int stride = gridDim.x * blockDim.x;
  const f32x4* W4 = (const f32x4*)W;
  int n4 = n >> 2;
  float s = 0.f;
  for (int i = tid; i < n4; i += stride) {
    f32x4 v = W4[i];
    s += fabsf(v[0]) + fabsf(v[1]) + fabsf(v[2]) + fabsf(v[3]);
  }
#pragma unroll
  for (int off = 32; off > 0; off >>= 1) s += __shfl_down(s, off, 64);
  __shared__ float wsum[4];
  if ((threadIdx.x & 63) == 0) wsum[threadIdx.x >> 6] = s;
  __syncthreads();
  if (threadIdx.x == 0)
    partials[blockIdx.x] = wsum[0] + wsum[1] + wsum[2] + wsum[3];
}

__global__ void gamma_finalize(const float* __restrict__ partials,
                               float* __restrict__ gamma, float inv_n) {
  __shared__ float sm[256];
  int t = threadIdx.x;
  sm[t] = partials[t] + partials[t + 256] + partials[t + 512] + partials[t + 768];
  __syncthreads();
  for (int off = 128; off > 0; off >>= 1) {
    if (t < off) sm[t] += sm[t + off];
    __syncthreads();
  }
  if (t == 0) gamma[0] = sm[0] * inv_n;
}

// ---------------- W -> ternary bf16 (exact {-1,0,1}) --------------------------
__global__ void quantize_w(const float* __restrict__ W,
                           unsigned short* __restrict__ Wq,
                           const float* __restrict__ gamma_p, int n) {
  float g = gamma_p[0];
  float safe = (g == 0.f) ? 1.f : g;
  int tid = blockIdx.x * blockDim.x + threadIdx.x;
  int stride = gridDim.x * blockDim.x;
  const f32x4* W4 = (const f32x4*)W;
  int n4 = n >> 2;
  for (int i = tid; i < n4; i += stride) {
    f32x4 v = W4[i];
    ushort4 q;
    float t0 = rintf(v[0] / safe);
    float t1 = rintf(v[1] / safe);
    float t2 = rintf(v[2] / safe);
    float t3 = rintf(v[3] / safe);
    q.x = (t0 >= 0.5f) ? 0x3F80u : (t0 <= -0.5f ? 0xBF80u : 0u);
    q.y = (t1 >= 0.5f) ? 0x3F80u : (t1 <= -0.5f ? 0xBF80u : 0u);
    q.z = (t2 >= 0.5f) ? 0x3F80u : (t2 <= -0.5f ? 0xBF80u : 0u);
    q.w = (t3 >= 0.5f) ? 0x3F80u : (t3 <= -0.5f ? 0xBF80u : 0u);
    ((ushort4*)Wq)[i] = q;
  }
}

// ---------------- x fp32 -> bf16 (RTN-even) -----------------------------------
__global__ void convert_x(const float* __restrict__ X,
                          unsigned short* __restrict__ Xb, int n) {
  int tid = blockIdx.x * blockDim.x + threadIdx.x;
  int stride = gridDim.x * blockDim.x;
  const f32x4* X4 = (const f32x4*)X;
  int n4 = n >> 2;
  for (int i = tid; i < n4; i += stride) {
    f32x4 v = X4[i];
    ushort4 o;
    unsigned u0 = __float_as_uint(v[0]);
    unsigned u1 = __float_as_uint(v[1]);
    unsigned u2 = __float_as_uint(v[2]);
    unsigned u3 = __float_as_uint(v[3]);
    o.x = (unsigned short)((u0 + 0x7FFFu + ((u0 >> 16) & 1u)) >> 16);
    o.y = (unsigned short)((u1 + 0x7FFFu + ((u1 >> 16) & 1u)) >> 16);
    o.z = (unsigned short)((u2 + 0x7FFFu + ((u2 >> 16) & 1u)) >> 16);
    o.w = (unsigned short)((u3 + 0x7FFFu + ((u3 >> 16) & 1u)) >> 16);
    ((ushort4*)Xb)[i] = o;
  }
}

// ---------------- 256x256 8-phase bf16 GEMM (T3+T4+T5, ring-4 BK=32) ----------
// A: [M][K] bf16 (x), B: [N][K] bf16 (W_q). 512 threads = 8 waves (2Mx4N),
// wave computes 128x64 = 8x4 fragments of 16x16x32. K-tile = 32, ring of 4
// LDS slots per matrix ([256][32] bf16 = 16KB; 64B rows -> bank-optimal b128
// reads without swizzle). Phase = {ds_read 4|8 b128; stage 1 half-tile;
// bar; lgkmcnt(0); setprio(1); 16 MFMA; setprio(0); bar}. Counted vmcnt(4)
// once per 4 phases; never 0 until the epilogue boundary (it==62).
__global__ __launch_bounds__(512, 2)
void gemm256_8ph(const unsigned short* __restrict__ A,
                 const unsigned short* __restrict__ Bq,
                 float* __restrict__ C,
                 const float* __restrict__ gamma_p, int M, int N) {
  __shared__ __align__(16) unsigned short Abuf[4][256][32];  // 64 KiB
  __shared__ __align__(16) unsigned short Bbuf[4][256][32];  // 64 KiB

  int ntN = N >> 8;
  int bid = blockIdx.x;
  int swz = (bid & 7) * (gridDim.x >> 3) + (bid >> 3);  // nwg % 8 == 0
  int tm = swz / ntN, tn = swz % ntN;

  int t = threadIdx.x;
  int lane = t & 63;
  int wid = t >> 6;
  int wr = wid >> 2, wc = wid & 3;   // 2 x 4 wave grid
  int lr = lane & 15;
  int lk = (lane >> 4) << 3;         // k element offset {0,8,16,24}

  const char* aG = (const char*)(A + (size_t)tm * 256 * K_DIM);
  const char* bG = (const char*)(Bq + (size_t)tn * 256 * K_DIM);

  // staging: thread t covers 16B at (row = c*128 + t/4, colbyte = (t%4)*16)
  int srow = t >> 2;
  int scolb = (t & 3) << 4;
  const char* aSg = aG + (size_t)srow * (K_DIM * 2) + scolb;
  const char* bSg = bG + (size_t)srow * (K_DIM * 2) + scolb;
  char* aSl = (char*)Abuf + t * 16;
  char* bSl = (char*)Bbuf + t * 16;

  const unsigned short* aRd = &Abuf[0][0][0] + (wr * 128 + lr) * 32 + lk;
  const unsigned short* bRd = &Bbuf[0][0][0] + (wc * 64 + lr) * 32 + lk;

  f32x4 acc[8][4];
#pragma unroll
  for (int m = 0; m < 8; ++m)
#pragma unroll
    for (int n = 0; n < 4; ++n) acc[m][n] = (f32x4)(0.f);

#define STAGE_A(jj)                                                            \
  { GLOAD_LDS16(aSg + (size_t)(jj) * 64, aSl + ((jj) & 3) * 16384);            \
    GLOAD_LDS16(aSg + (size_t)(jj) * 64 + (size_t)128 * K_DIM * 2,             \
                aSl + ((jj) & 3) * 16384 + 8192); }
#define STAGE_B(jj)                                                            \
  { GLOAD_LDS16(bSg + (size_t)(jj) * 64, bSl + ((jj) & 3) * 16384);            \
    GLOAD_LDS16(bSg + (size_t)(jj) * 64 + (size_t)128 * K_DIM * 2,             \
                bSl + ((jj) & 3) * 16384 + 8192); }
#define DS_A(SLOT, MH)                                                         \
  { _Pragma("unroll") for (int m = 0; m < 4; ++m)                              \
      af[m] = *(const short8*)(aRd + (SLOT) * 8192 + (MH) * 2048 + m * 512); }
#define DS_B(SLOT)                                                             \
  { _Pragma("unroll") for (int n = 0; n < 4; ++n)                              \
      bf[n] = *(const short8*)(bRd + (SLOT) * 8192 + n * 512); }
#define MFMA_PH(MH)                                                            \
  { _Pragma("unroll") for (int m = 0; m < 4; ++m)                              \
      _Pragma("unroll") for (int n = 0; n < 4; ++n)                            \
        acc[(MH) * 4 + m][n] = __builtin_amdgcn_mfma_f32_16x16x32_bf16(        \
            af[m], bf[n], acc[(MH) * 4 + m][n], 0, 0, 0); }
#define BAR() __builtin_amdgcn_s_barrier()
#define LGKM0() asm volatile("s_waitcnt lgkmcnt(0)" ::: "memory")

  // prologue: stage kt 0,1,2 (12 loads), drain through kt1, keep kt2 in flight
  STAGE_A(0); STAGE_B(0); STAGE_A(1); STAGE_B(1); STAGE_A(2); STAGE_B(2);
  asm volatile("s_waitcnt vmcnt(4)" ::: "memory");
  BAR();

  short8 af[4], bf[4];
  for (int it = 0; it < 64; ++it) {
    int kt0 = it << 1;
    int s0 = kt0 & 3, s1 = (kt0 + 1) & 3;
    int j0 = kt0 + 3, j1 = kt0 + 4;
    // ---- phase 0: kt0, m-half 0 (reads B + A = 8 b128) ----
    DS_B(s0);
    DS_A(s0, 0);
    if (j0 < NKT) STAGE_A(j0);
    BAR(); LGKM0();
    __builtin_amdgcn_s_setprio(1); MFMA_PH(0); __builtin_amdgcn_s_setprio(0);
    BAR();
    // ---- phase 1: kt0, m-half 1 (reads A = 4 b128, B reused) ----
    DS_A(s0, 1);
    if (j0 < NKT) STAGE_B(j0);
    BAR(); LGKM0();
    __builtin_amdgcn_s_setprio(1); MFMA_PH(1); __builtin_amdgcn_s_setprio(0);
    BAR();
    // ---- phase 2: kt1, m-half 0 ----
    DS_B(s1);
    DS_A(s1, 0);
    if (j1 < NKT) STAGE_A(j1);
    BAR(); LGKM0();
    __builtin_amdgcn_s_setprio(1); MFMA_PH(0); __builtin_amdgcn_s_setprio(0);
    BAR();
    // ---- phase 3: kt1, m-half 1 + K-tile-pair boundary vmcnt ----
    DS_A(s1, 1);
    if (j1 < NKT) STAGE_B(j1);
    BAR(); LGKM0();
    __builtin_amdgcn_s_setprio(1); MFMA_PH(1); __builtin_amdgcn_s_setprio(0);
    if (it < 62) {
      asm volatile("s_waitcnt vmcnt(4)" ::: "memory");
    } else if (it == 62) {
      asm volatile("s_waitcnt vmcnt(0)" ::: "memory");
    }
    BAR();
  }

  float g = gamma_p[0];
  int crow = (lane >> 4) << 2;   // C/D: col = lane&15, row = (lane>>4)*4 + reg
  size_t row0 = (size_t)tm * 256 + wr * 128 + crow;
  int col0 = tn * 256 + wc * 64 + lr;
#pragma unroll
  for (int m = 0; m < 8; ++m) {
#pragma unroll
    for (int j = 0; j < 4; ++j) {
      float* cp = C + (row0 + m * 16 + j) * (size_t)N + col0;
#pragma unroll
      for (int n = 0; n < 4; ++n) cp[n * 16] = acc[m][n][j] * g;
    }
  }
#undef STAGE_A
#undef STAGE_B
#undef DS_A
#undef DS_B
#undef MFMA_PH
#undef BAR
#undef LGKM0
}

// ---------------- naive fallback (only if ws too small / odd shapes) ----------
__global__ void naive_bitlinear(const float* __restrict__ X,
                                const float* __restrict__ W,
                                float* __restrict__ out,
                                const float* __restrict__ gamma_p, int M, int N) {
  int col = blockIdx.x * blockDim.x + threadIdx.x;
  int row = blockIdx.y;
  if (col >= N || row >= M) return;
  float g = gamma_p[0];
  float safe = (g == 0.f) ? 1.f : g;
  const float* x = X + (size_t)row * K_DIM;
  const float* w = W + (size_t)col * K_DIM;
  float s = 0.f;
  for (int k = 0; k < K_DIM; ++k) {
    float qv = fminf(fmaxf(rintf(w[k] / safe), -1.f), 1.f);
    s += x[k] * qv;
  }
  out[(size_t)row * N + col] = s * g;
}

extern "C" void kernel_launch(void* const* d_in, const int* in_sizes, int n_in,
                              void* d_out, int out_size, void* d_ws,
                              size_t ws_size, hipStream_t stream) {
  const float* x = (const float*)d_in[0];
  const float* w = (const float*)d_in[1];
  float* out = (float*)d_out;
  int xn = in_sizes[0];   // B*S*D_IN = 33554432
  int wn = in_sizes[1];   // D_OUT*D_IN = 16777216
  int M = xn / K_DIM;     // 8192
  int N = wn / K_DIM;     // 4096

  char* ws = (char*)d_ws;
  float* partials = (float*)ws;                       // 1024 floats
  float* gamma = (float*)(ws + 4096);                 // 1 float
  unsigned short* Wq = (unsigned short*)(ws + 8192);  // N*K bf16
  unsigned short* Xb = Wq + (size_t)wn;               // M*K bf16
  size_t need = 8192 + (size_t)wn * 2 + (size_t)xn * 2;

  absum_partial<<<1024, 256, 0, stream>>>(w, partials, wn);
  gamma_finalize<<<1, 256, 0, stream>>>(partials, gamma, 1.0f / (float)wn);

  if (ws_size >= need && (M & 255) == 0 && (N & 255) == 0) {
    quantize_w<<<2048, 256, 0, stream>>>(w, Wq, gamma, wn);
    convert_x<<<2048, 256, 0, stream>>>(x, Xb, xn);
    int nwg = (M >> 8) * (N >> 8);   // 32 * 16 = 512
    gemm256_8ph<<<nwg, 512, 0, stream>>>(Xb, Wq, out, gamma, M, N);
  } else {
    dim3 grid((N + 255) / 256, M);
    naive_bitlinear<<<grid, 256, 0, stream>>>(x, w, out, gamma, M, N);
  }
}

// Round 3
// 316.210 us; speedup vs baseline: 1.1377x; 1.0373x over previous
//
#include <hip/hip_runtime.h>
#include <hip/hip_bf16.h>
#include <stdint.h>

#define K_DIM 4096
#define NKT   (K_DIM / 32)   // 128 K-tiles of BK=32

typedef __attribute__((ext_vector_type(4))) float f32x4;
typedef __attribute__((ext_vector_type(8))) short short8;

#define GLOAD_LDS16(g, l)                                                        \
  __builtin_amdgcn_global_load_lds(                                              \
      (const __attribute__((address_space(1))) void*)(g),                        \
      (__attribute__((address_space(3))) void*)(l), 16, 0, 0)

// ---------------- gamma = mean(|W|): deterministic 2-stage reduction ----------
__global__ void absum_partial(const float* __restrict__ W,
                              float* __restrict__ partials, int n) {
  int tid = blockIdx.x * blockDim.x + threadIdx.x;
  int stride = gridDim.x * blockDim.x;
  const f32x4* W4 = (const f32x4*)W;
  int n4 = n >> 2;
  float s = 0.f;
  for (int i = tid; i < n4; i += stride) {
    f32x4 v = W4[i];
    s += fabsf(v[0]) + fabsf(v[1]) + fabsf(v[2]) + fabsf(v[3]);
  }
#pragma unroll
  for (int off = 32; off > 0; off >>= 1) s += __shfl_down(s, off, 64);
  __shared__ float wsum[4];
  if ((threadIdx.x & 63) == 0) wsum[threadIdx.x >> 6] = s;
  __syncthreads();
  if (threadIdx.x == 0)
    partials[blockIdx.x] = wsum[0] + wsum[1] + wsum[2] + wsum[3];
}

__global__ void gamma_finalize(const float* __restrict__ partials,
                               float* __restrict__ gamma, float inv_n) {
  __shared__ float sm[256];
  int t = threadIdx.x;
  sm[t] = partials[t] + partials[t + 256] + partials[t + 512] + partials[t + 768];
  __syncthreads();
  for (int off = 128; off > 0; off >>= 1) {
    if (t < off) sm[t] += sm[t + off];
    __syncthreads();
  }
  if (t == 0) gamma[0] = sm[0] * inv_n;
}

// ---------------- W -> ternary bf16 (exact {-1,0,1}) --------------------------
__global__ void quantize_w(const float* __restrict__ W,
                           unsigned short* __restrict__ Wq,
                           const float* __restrict__ gamma_p, int n) {
  float g = gamma_p[0];
  float safe = (g == 0.f) ? 1.f : g;
  int tid = blockIdx.x * blockDim.x + threadIdx.x;
  int stride = gridDim.x * blockDim.x;
  const f32x4* W4 = (const f32x4*)W;
  int n4 = n >> 2;
  for (int i = tid; i < n4; i += stride) {
    f32x4 v = W4[i];
    ushort4 q;
    float t0 = rintf(v[0] / safe);
    float t1 = rintf(v[1] / safe);
    float t2 = rintf(v[2] / safe);
    float t3 = rintf(v[3] / safe);
    q.x = (t0 >= 0.5f) ? 0x3F80u : (t0 <= -0.5f ? 0xBF80u : 0u);
    q.y = (t1 >= 0.5f) ? 0x3F80u : (t1 <= -0.5f ? 0xBF80u : 0u);
    q.z = (t2 >= 0.5f) ? 0x3F80u : (t2 <= -0.5f ? 0xBF80u : 0u);
    q.w = (t3 >= 0.5f) ? 0x3F80u : (t3 <= -0.5f ? 0xBF80u : 0u);
    ((ushort4*)Wq)[i] = q;
  }
}

// ---------------- x fp32 -> bf16 (RTN-even) -----------------------------------
__global__ void convert_x(const float* __restrict__ X,
                          unsigned short* __restrict__ Xb, int n) {
  int tid = blockIdx.x * blockDim.x + threadIdx.x;
  int stride = gridDim.x * blockDim.x;
  const f32x4* X4 = (const f32x4*)X;
  int n4 = n >> 2;
  for (int i = tid; i < n4; i += stride) {
    f32x4 v = X4[i];
    ushort4 o;
    unsigned u0 = __float_as_uint(v[0]);
    unsigned u1 = __float_as_uint(v[1]);
    unsigned u2 = __float_as_uint(v[2]);
    unsigned u3 = __float_as_uint(v[3]);
    o.x = (unsigned short)((u0 + 0x7FFFu + ((u0 >> 16) & 1u)) >> 16);
    o.y = (unsigned short)((u1 + 0x7FFFu + ((u1 >> 16) & 1u)) >> 16);
    o.z = (unsigned short)((u2 + 0x7FFFu + ((u2 >> 16) & 1u)) >> 16);
    o.w = (unsigned short)((u3 + 0x7FFFu + ((u3 >> 16) & 1u)) >> 16);
    ((ushort4*)Xb)[i] = o;
  }
}

// ---------------- 256x256 8-phase bf16 GEMM (T2+T3+T4+T5, ring-4 BK=32) -------
// A: [M][K] bf16 (x), B: [N][K] bf16 (W_q). 512 threads = 8 waves (2Mx4N),
// wave computes 128x64 = 8x4 fragments of 16x16x32. K-tile = 32, ring of 4
// LDS slots per matrix ([256][32] bf16 = 16KB).
// T2 swizzle (rule #21: both-sides-or-neither): LDS[row][chunk q] holds
// global[row][q ^ ((row>>1)&3)] (16B chunks). Staging permutes the GLOBAL
// source chunk per thread (LDS dest stays linear for global_load_lds);
// fragment reads XOR the same value, folded into the per-thread base
// (row bits [2:1] == lr bits [2:1] for every fragment row). Result: each
// bank-quad hit exactly 2x per 16-lane group -> 2-way aliasing = free.
__global__ __launch_bounds__(512, 2)
void gemm256_8ph(const unsigned short* __restrict__ A,
                 const unsigned short* __restrict__ Bq,
                 float* __restrict__ C,
                 const float* __restrict__ gamma_p, int M, int N) {
  __shared__ __align__(16) unsigned short Abuf[4][256][32];  // 64 KiB
  __shared__ __align__(16) unsigned short Bbuf[4][256][32];  // 64 KiB

  int ntN = N >> 8;
  int bid = blockIdx.x;
  int swz = (bid & 7) * (gridDim.x >> 3) + (bid >> 3);  // nwg % 8 == 0
  int tm = swz / ntN, tn = swz % ntN;

  int t = threadIdx.x;
  int lane = t & 63;
  int wid = t >> 6;
  int wr = wid >> 2, wc = wid & 3;   // 2 x 4 wave grid
  int lr = lane & 15;
  // swizzled k-chunk offset (shorts): chunk (lane>>4) XOR row-dependent swizzle
  int lks = (((lane >> 4) ^ ((lr >> 1) & 3)) << 3);

  const char* aG = (const char*)(A + (size_t)tm * 256 * K_DIM);
  const char* bG = (const char*)(Bq + (size_t)tn * 256 * K_DIM);

  // staging: thread t covers LDS 16B chunk (row = t>>2, chunk = t&3);
  // source chunk = (t&3) ^ ((row>>1)&3)  [row>>1 bits = (t>>3)&3]
  int srow = t >> 2;
  int schunk = (t & 3) ^ ((t >> 3) & 3);
  const char* aSg = aG + (size_t)srow * (K_DIM * 2) + (schunk << 4);
  const char* bSg = bG + (size_t)srow * (K_DIM * 2) + (schunk << 4);
  char* aSl = (char*)Abuf + t * 16;
  char* bSl = (char*)Bbuf + t * 16;

  const unsigned short* aRd = &Abuf[0][0][0] + (wr * 128 + lr) * 32 + lks;
  const unsigned short* bRd = &Bbuf[0][0][0] + (wc * 64 + lr) * 32 + lks;

  f32x4 acc[8][4];
#pragma unroll
  for (int m = 0; m < 8; ++m)
#pragma unroll
    for (int n = 0; n < 4; ++n) acc[m][n] = (f32x4)(0.f);

#define STAGE_A(jj)                                                            \
  { GLOAD_LDS16(aSg + (size_t)(jj) * 64, aSl + ((jj) & 3) * 16384);            \
    GLOAD_LDS16(aSg + (size_t)(jj) * 64 + (size_t)128 * K_DIM * 2,             \
                aSl + ((jj) & 3) * 16384 + 8192); }
#define STAGE_B(jj)                                                            \
  { GLOAD_LDS16(bSg + (size_t)(jj) * 64, bSl + ((jj) & 3) * 16384);            \
    GLOAD_LDS16(bSg + (size_t)(jj) * 64 + (size_t)128 * K_DIM * 2,             \
                bSl + ((jj) & 3) * 16384 + 8192); }
#define DS_A(SLOT, MH)                                                         \
  { _Pragma("unroll") for (int m = 0; m < 4; ++m)                              \
      af[m] = *(const short8*)(aRd + (SLOT) * 8192 + (MH) * 2048 + m * 512); }
#define DS_B(SLOT)                                                             \
  { _Pragma("unroll") for (int n = 0; n < 4; ++n)                              \
      bf[n] = *(const short8*)(bRd + (SLOT) * 8192 + n * 512); }
#define MFMA_PH(MH)                                                            \
  { _Pragma("unroll") for (int m = 0; m < 4; ++m)                              \
      _Pragma("unroll") for (int n = 0; n < 4; ++n)                            \
        acc[(MH) * 4 + m][n] = __builtin_amdgcn_mfma_f32_16x16x32_bf16(        \
            af[m], bf[n], acc[(MH) * 4 + m][n], 0, 0, 0); }
#define BAR() __builtin_amdgcn_s_barrier()
#define LGKM0() asm volatile("s_waitcnt lgkmcnt(0)" ::: "memory")

  // prologue: stage kt 0,1,2 (12 loads), drain through kt1, keep kt2 in flight
  STAGE_A(0); STAGE_B(0); STAGE_A(1); STAGE_B(1); STAGE_A(2); STAGE_B(2);
  asm volatile("s_waitcnt vmcnt(4)" ::: "memory");
  BAR();

  short8 af[4], bf[4];
  for (int it = 0; it < 64; ++it) {
    int kt0 = it << 1;
    int s0 = kt0 & 3, s1 = (kt0 + 1) & 3;
    int j0 = kt0 + 3, j1 = kt0 + 4;
    // ---- phase 0: kt0, m-half 0 (reads B + A = 8 b128) ----
    DS_B(s0);
    DS_A(s0, 0);
    if (j0 < NKT) STAGE_A(j0);
    BAR(); LGKM0();
    __builtin_amdgcn_s_setprio(1); MFMA_PH(0); __builtin_amdgcn_s_setprio(0);
    BAR();
    // ---- phase 1: kt0, m-half 1 (reads A = 4 b128, B reused) ----
    DS_A(s0, 1);
    if (j0 < NKT) STAGE_B(j0);
    BAR(); LGKM0();
    __builtin_amdgcn_s_setprio(1); MFMA_PH(1); __builtin_amdgcn_s_setprio(0);
    BAR();
    // ---- phase 2: kt1, m-half 0 ----
    DS_B(s1);
    DS_A(s1, 0);
    if (j1 < NKT) STAGE_A(j1);
    BAR(); LGKM0();
    __builtin_amdgcn_s_setprio(1); MFMA_PH(0); __builtin_amdgcn_s_setprio(0);
    BAR();
    // ---- phase 3: kt1, m-half 1 + K-tile-pair boundary vmcnt ----
    DS_A(s1, 1);
    if (j1 < NKT) STAGE_B(j1);
    BAR(); LGKM0();
    __builtin_amdgcn_s_setprio(1); MFMA_PH(1); __builtin_amdgcn_s_setprio(0);
    if (it < 62) {
      asm volatile("s_waitcnt vmcnt(4)" ::: "memory");
    } else if (it == 62) {
      asm volatile("s_waitcnt vmcnt(0)" ::: "memory");
    }
    BAR();
  }

  float g = gamma_p[0];
  int crow = (lane >> 4) << 2;   // C/D: col = lane&15, row = (lane>>4)*4 + reg
  size_t row0 = (size_t)tm * 256 + wr * 128 + crow;
  int col0 = tn * 256 + wc * 64 + lr;
#pragma unroll
  for (int m = 0; m < 8; ++m) {
#pragma unroll
    for (int j = 0; j < 4; ++j) {
      float* cp = C + (row0 + m * 16 + j) * (size_t)N + col0;
#pragma unroll
      for (int n = 0; n < 4; ++n) cp[n * 16] = acc[m][n][j] * g;
    }
  }
#undef STAGE_A
#undef STAGE_B
#undef DS_A
#undef DS_B
#undef MFMA_PH
#undef BAR
#undef LGKM0
}

// ---------------- naive fallback (only if ws too small / odd shapes) ----------
__global__ void naive_bitlinear(const float* __restrict__ X,
                                const float* __restrict__ W,
                                float* __restrict__ out,
                                const float* __restrict__ gamma_p, int M, int N) {
  int col = blockIdx.x * blockDim.x + threadIdx.x;
  int row = blockIdx.y;
  if (col >= N || row >= M) return;
  float g = gamma_p[0];
  float safe = (g == 0.f) ? 1.f : g;
  const float* x = X + (size_t)row * K_DIM;
  const float* w = W + (size_t)col * K_DIM;
  float s = 0.f;
  for (int k = 0; k < K_DIM; ++k) {
    float qv = fminf(fmaxf(rintf(w[k] / safe), -1.f), 1.f);
    s += x[k] * qv;
  }
  out[(size_t)row * N + col] = s * g;
}

extern "C" void kernel_launch(void* const* d_in, const int* in_sizes, int n_in,
                              void* d_out, int out_size, void* d_ws,
                              size_t ws_size, hipStream_t stream) {
  const float* x = (const float*)d_in[0];
  const float* w = (const float*)d_in[1];
  float* out = (float*)d_out;
  int xn = in_sizes[0];   // B*S*D_IN = 33554432
  int wn = in_sizes[1];   // D_OUT*D_IN = 16777216
  int M = xn / K_DIM;     // 8192
  int N = wn / K_DIM;     // 4096

  char* ws = (char*)d_ws;
  float* partials = (float*)ws;                       // 1024 floats
  float* gamma = (float*)(ws + 4096);                 // 1 float
  unsigned short* Wq = (unsigned short*)(ws + 8192);  // N*K bf16
  unsigned short* Xb = Wq + (size_t)wn;               // M*K bf16
  size_t need = 8192 + (size_t)wn * 2 + (size_t)xn * 2;

  absum_partial<<<1024, 256, 0, stream>>>(w, partials, wn);
  gamma_finalize<<<1, 256, 0, stream>>>(partials, gamma, 1.0f / (float)wn);

  if (ws_size >= need && (M & 255) == 0 && (N & 255) == 0) {
    quantize_w<<<2048, 256, 0, stream>>>(w, Wq, gamma, wn);
    convert_x<<<2048, 256, 0, stream>>>(x, Xb, xn);
    int nwg = (M >> 8) * (N >> 8);   // 32 * 16 = 512
    gemm256_8ph<<<nwg, 512, 0, stream>>>(Xb, Wq, out, gamma, M, N);
  } else {
    dim3 grid((N + 255) / 256, M);
    naive_bitlinear<<<grid, 256, 0, stream>>>(x, w, out, gamma, M, N);
  }
}

// Round 4
// 305.469 us; speedup vs baseline: 1.1777x; 1.0352x over previous
//
#include <hip/hip_runtime.h>
#include <hip/hip_bf16.h>
#include <stdint.h>

#define K_DIM 4096
#define NKT   (K_DIM / 32)   // 128 K-tiles of BK=32

typedef __attribute__((ext_vector_type(4))) float f32x4;
typedef __attribute__((ext_vector_type(8))) short short8;

#define GLOAD_LDS16(g, l)                                                        \
  __builtin_amdgcn_global_load_lds(                                              \
      (const __attribute__((address_space(1))) void*)(g),                        \
      (__attribute__((address_space(3))) void*)(l), 16, 0, 0)

// ---------------- gamma = mean(|W|): deterministic 2-stage reduction ----------
__global__ void absum_partial(const float* __restrict__ W,
                              float* __restrict__ partials, int n) {
  int tid = blockIdx.x * blockDim.x + threadIdx.x;
  int stride = gridDim.x * blockDim.x;
  const f32x4* W4 = (const f32x4*)W;
  int n4 = n >> 2;
  float s = 0.f;
  for (int i = tid; i < n4; i += stride) {
    f32x4 v = W4[i];
    s += fabsf(v[0]) + fabsf(v[1]) + fabsf(v[2]) + fabsf(v[3]);
  }
#pragma unroll
  for (int off = 32; off > 0; off >>= 1) s += __shfl_down(s, off, 64);
  __shared__ float wsum[4];
  if ((threadIdx.x & 63) == 0) wsum[threadIdx.x >> 6] = s;
  __syncthreads();
  if (threadIdx.x == 0)
    partials[blockIdx.x] = wsum[0] + wsum[1] + wsum[2] + wsum[3];
}

__global__ void gamma_finalize(const float* __restrict__ partials,
                               float* __restrict__ gamma, float inv_n) {
  __shared__ float sm[256];
  int t = threadIdx.x;
  sm[t] = partials[t] + partials[t + 256] + partials[t + 512] + partials[t + 768];
  __syncthreads();
  for (int off = 128; off > 0; off >>= 1) {
    if (t < off) sm[t] += sm[t + off];
    __syncthreads();
  }
  if (t == 0) gamma[0] = sm[0] * inv_n;
}

// ---------------- W -> ternary bf16 (exact {-1,0,1}) --------------------------
__global__ void quantize_w(const float* __restrict__ W,
                           unsigned short* __restrict__ Wq,
                           const float* __restrict__ gamma_p, int n) {
  float g = gamma_p[0];
  float safe = (g == 0.f) ? 1.f : g;
  int tid = blockIdx.x * blockDim.x + threadIdx.x;
  int stride = gridDim.x * blockDim.x;
  const f32x4* W4 = (const f32x4*)W;
  int n4 = n >> 2;
  for (int i = tid; i < n4; i += stride) {
    f32x4 v = W4[i];
    ushort4 q;
    float t0 = rintf(v[0] / safe);
    float t1 = rintf(v[1] / safe);
    float t2 = rintf(v[2] / safe);
    float t3 = rintf(v[3] / safe);
    q.x = (t0 >= 0.5f) ? 0x3F80u : (t0 <= -0.5f ? 0xBF80u : 0u);
    q.y = (t1 >= 0.5f) ? 0x3F80u : (t1 <= -0.5f ? 0xBF80u : 0u);
    q.z = (t2 >= 0.5f) ? 0x3F80u : (t2 <= -0.5f ? 0xBF80u : 0u);
    q.w = (t3 >= 0.5f) ? 0x3F80u : (t3 <= -0.5f ? 0xBF80u : 0u);
    ((ushort4*)Wq)[i] = q;
  }
}

// ---------------- x fp32 -> bf16 (RTN-even) -----------------------------------
__global__ void convert_x(const float* __restrict__ X,
                          unsigned short* __restrict__ Xb, int n) {
  int tid = blockIdx.x * blockDim.x + threadIdx.x;
  int stride = gridDim.x * blockDim.x;
  const f32x4* X4 = (const f32x4*)X;
  int n4 = n >> 2;
  for (int i = tid; i < n4; i += stride) {
    f32x4 v = X4[i];
    ushort4 o;
    unsigned u0 = __float_as_uint(v[0]);
    unsigned u1 = __float_as_uint(v[1]);
    unsigned u2 = __float_as_uint(v[2]);
    unsigned u3 = __float_as_uint(v[3]);
    o.x = (unsigned short)((u0 + 0x7FFFu + ((u0 >> 16) & 1u)) >> 16);
    o.y = (unsigned short)((u1 + 0x7FFFu + ((u1 >> 16) & 1u)) >> 16);
    o.z = (unsigned short)((u2 + 0x7FFFu + ((u2 >> 16) & 1u)) >> 16);
    o.w = (unsigned short)((u3 + 0x7FFFu + ((u3 >> 16) & 1u)) >> 16);
    ((ushort4*)Xb)[i] = o;
  }
}

// ---------------- 256x256 bf16 GEMM: merged phases, 32 MFMA / barrier-pair ----
// 512 threads = 8 waves (2Mx4N), wave output 128x64 (8x4 frags 16x16x32).
// K-tile = 32, ring-4 LDS slots ([256][32] bf16 = 16KB each, A+B = 128KiB).
// Phase p (one per K-tile): {stage tile p+3 (4 gload_lds); issue 12 ds_read
// (B, A-h0, A-h1); BAR; lgkmcnt(4); prio1; 16 MFMA h0; lgkmcnt(0); 16 MFMA
// h1; prio0; vmcnt(8); BAR}. Counted vmcnt keeps tiles p+2,p+3 (8 loads) in
// flight across barriers; tail drains 8->4->0. vmcnt precedes BAR so the
// barrier publishes every wave's staging (vmcnt is per-wave).
// T2 swizzle (both-sides): LDS[row][q] = global[row][q ^ ((row>>1)&3)];
// staging permutes the GLOBAL chunk (LDS dest linear, rule #21); reads fold
// the same XOR into the base (row bits[2:1]==lr bits[2:1] for all frags).
__global__ __launch_bounds__(512, 2)
void gemm256_m(const unsigned short* __restrict__ A,
               const unsigned short* __restrict__ Bq,
               float* __restrict__ C,
               const float* __restrict__ gamma_p, int M, int N) {
  __shared__ __align__(16) unsigned short Abuf[4][256][32];  // 64 KiB
  __shared__ __align__(16) unsigned short Bbuf[4][256][32];  // 64 KiB

  int ntN = N >> 8;
  int bid = blockIdx.x;
  int swz = (bid & 7) * (gridDim.x >> 3) + (bid >> 3);  // nwg % 8 == 0
  int tm = swz / ntN, tn = swz % ntN;

  int t = threadIdx.x;
  int lane = t & 63;
  int wid = t >> 6;
  int wr = wid >> 2, wc = wid & 3;   // 2 x 4 wave grid
  int lr = lane & 15;
  int lks = (((lane >> 4) ^ ((lr >> 1) & 3)) << 3);  // swizzled k-chunk (shorts)

  const char* aG = (const char*)(A + (size_t)tm * 256 * K_DIM);
  const char* bG = (const char*)(Bq + (size_t)tn * 256 * K_DIM);

  // staging: thread t -> LDS 16B chunk (row = t>>2, chunk = t&3);
  // global source chunk = (t&3) ^ ((row>>1)&3)
  int srow = t >> 2;
  int schunk = (t & 3) ^ ((t >> 3) & 3);
  const char* aSg = aG + (size_t)srow * (K_DIM * 2) + (schunk << 4);
  const char* bSg = bG + (size_t)srow * (K_DIM * 2) + (schunk << 4);
  char* aSl = (char*)Abuf + t * 16;
  char* bSl = (char*)Bbuf + t * 16;

  const unsigned short* aRd = &Abuf[0][0][0] + (wr * 128 + lr) * 32 + lks;
  const unsigned short* bRd = &Bbuf[0][0][0] + (wc * 64 + lr) * 32 + lks;

  f32x4 acc[8][4];
#pragma unroll
  for (int m = 0; m < 8; ++m)
#pragma unroll
    for (int n = 0; n < 4; ++n) acc[m][n] = (f32x4)(0.f);

#define STAGE_A(jj)                                                            \
  { GLOAD_LDS16(aSg + (size_t)(jj) * 64, aSl + ((jj) & 3) * 16384);            \
    GLOAD_LDS16(aSg + (size_t)(jj) * 64 + (size_t)128 * K_DIM * 2,             \
                aSl + ((jj) & 3) * 16384 + 8192); }
#define STAGE_B(jj)                                                            \
  { GLOAD_LDS16(bSg + (size_t)(jj) * 64, bSl + ((jj) & 3) * 16384);            \
    GLOAD_LDS16(bSg + (size_t)(jj) * 64 + (size_t)128 * K_DIM * 2,             \
                bSl + ((jj) & 3) * 16384 + 8192); }
#define BAR() __builtin_amdgcn_s_barrier()
#define VMC(NN) asm volatile("s_waitcnt vmcnt(" #NN ")" ::: "memory")

  // PHASE(S: compile-time slot, J: stage tile idx, DOSTG, VMSTMT)
#define PHASE(S, J, DOSTG, VMSTMT)                                             \
  {                                                                            \
    if (DOSTG) { STAGE_A(J); STAGE_B(J); }                                     \
    _Pragma("unroll") for (int n = 0; n < 4; ++n)                              \
      bf[n] = *(const short8*)(bRd + (S) * 8192 + n * 512);                    \
    _Pragma("unroll") for (int m = 0; m < 4; ++m)                              \
      af0[m] = *(const short8*)(aRd + (S) * 8192 + m * 512);                   \
    _Pragma("unroll") for (int m = 0; m < 4; ++m)                              \
      af1[m] = *(const short8*)(aRd + (S) * 8192 + 2048 + m * 512);            \
    BAR();                                                                     \
    asm volatile("s_waitcnt lgkmcnt(4)" ::: "memory");                         \
    __builtin_amdgcn_s_setprio(1);                                             \
    _Pragma("unroll") for (int m = 0; m < 4; ++m)                              \
      _Pragma("unroll") for (int n = 0; n < 4; ++n)                            \
        acc[m][n] = __builtin_amdgcn_mfma_f32_16x16x32_bf16(af0[m], bf[n],     \
                                                            acc[m][n], 0, 0, 0);\
    asm volatile("s_waitcnt lgkmcnt(0)" ::: "memory");                         \
    _Pragma("unroll") for (int m = 0; m < 4; ++m)                              \
      _Pragma("unroll") for (int n = 0; n < 4; ++n)                            \
        acc[4 + m][n] = __builtin_amdgcn_mfma_f32_16x16x32_bf16(af1[m], bf[n], \
                                                        acc[4 + m][n], 0, 0, 0);\
    __builtin_amdgcn_s_setprio(0);                                             \
    VMSTMT;                                                                    \
    BAR();                                                                     \
  }

  // prologue: stage tiles 0,1,2 (12 loads); tile 0 ready, 8 in flight
  STAGE_A(0); STAGE_B(0); STAGE_A(1); STAGE_B(1); STAGE_A(2); STAGE_B(2);
  VMC(8);
  BAR();

  short8 af0[4], af1[4], bf[4];
  // uniform body: phases p = 0..123 (31 iters x 4), stage p+3, vmcnt(8)
  for (int it = 0; it < 31; ++it) {
    int p0 = it << 2;
    PHASE(0, p0 + 3, 1, VMC(8));
    PHASE(1, p0 + 4, 1, VMC(8));
    PHASE(2, p0 + 5, 1, VMC(8));
    PHASE(3, p0 + 6, 1, VMC(8));
  }
  // tail: p = 124 (stage 127, vmcnt(8)), 125 (vmcnt(4)), 126 (vmcnt(0)), 127
  PHASE(0, 127, 1, VMC(8));
  PHASE(1, 0, 0, VMC(4));
  PHASE(2, 0, 0, VMC(0));
  PHASE(3, 0, 0, (void)0);

  float g = gamma_p[0];
  int crow = (lane >> 4) << 2;   // C/D: col = lane&15, row = (lane>>4)*4 + reg
  size_t row0 = (size_t)tm * 256 + wr * 128 + crow;
  int col0 = tn * 256 + wc * 64 + lr;
#pragma unroll
  for (int m = 0; m < 8; ++m) {
#pragma unroll
    for (int j = 0; j < 4; ++j) {
      float* cp = C + (row0 + m * 16 + j) * (size_t)N + col0;
#pragma unroll
      for (int n = 0; n < 4; ++n) cp[n * 16] = acc[m][n][j] * g;
    }
  }
#undef STAGE_A
#undef STAGE_B
#undef BAR
#undef VMC
#undef PHASE
}

// ---------------- naive fallback (only if ws too small / odd shapes) ----------
__global__ void naive_bitlinear(const float* __restrict__ X,
                                const float* __restrict__ W,
                                float* __restrict__ out,
                                const float* __restrict__ gamma_p, int M, int N) {
  int col = blockIdx.x * blockDim.x + threadIdx.x;
  int row = blockIdx.y;
  if (col >= N || row >= M) return;
  float g = gamma_p[0];
  float safe = (g == 0.f) ? 1.f : g;
  const float* x = X + (size_t)row * K_DIM;
  const float* w = W + (size_t)col * K_DIM;
  float s = 0.f;
  for (int k = 0; k < K_DIM; ++k) {
    float qv = fminf(fmaxf(rintf(w[k] / safe), -1.f), 1.f);
    s += x[k] * qv;
  }
  out[(size_t)row * N + col] = s * g;
}

extern "C" void kernel_launch(void* const* d_in, const int* in_sizes, int n_in,
                              void* d_out, int out_size, void* d_ws,
                              size_t ws_size, hipStream_t stream) {
  const float* x = (const float*)d_in[0];
  const float* w = (const float*)d_in[1];
  float* out = (float*)d_out;
  int xn = in_sizes[0];   // B*S*D_IN = 33554432
  int wn = in_sizes[1];   // D_OUT*D_IN = 16777216
  int M = xn / K_DIM;     // 8192
  int N = wn / K_DIM;     // 4096

  char* ws = (char*)d_ws;
  float* partials = (float*)ws;                       // 1024 floats
  float* gamma = (float*)(ws + 4096);                 // 1 float
  unsigned short* Wq = (unsigned short*)(ws + 8192);  // N*K bf16
  unsigned short* Xb = Wq + (size_t)wn;               // M*K bf16
  size_t need = 8192 + (size_t)wn * 2 + (size_t)xn * 2;

  absum_partial<<<1024, 256, 0, stream>>>(w, partials, wn);
  gamma_finalize<<<1, 256, 0, stream>>>(partials, gamma, 1.0f / (float)wn);

  if (ws_size >= need && (M & 255) == 0 && (N & 255) == 0) {
    quantize_w<<<2048, 256, 0, stream>>>(w, Wq, gamma, wn);
    convert_x<<<2048, 256, 0, stream>>>(x, Xb, xn);
    int nwg = (M >> 8) * (N >> 8);   // 32 * 16 = 512
    gemm256_m<<<nwg, 512, 0, stream>>>(Xb, Wq, out, gamma, M, N);
  } else {
    dim3 grid((N + 255) / 256, M);
    naive_bitlinear<<<grid, 256, 0, stream>>>(x, w, out, gamma, M, N);
  }
}

// Round 5
// 303.928 us; speedup vs baseline: 1.1837x; 1.0051x over previous
//
#include <hip/hip_runtime.h>
#include <hip/hip_bf16.h>
#include <stdint.h>

#define K_DIM 4096
#define NKT   (K_DIM / 32)   // 128 K-tiles of BK=32

typedef __attribute__((ext_vector_type(4))) float f32x4;
typedef __attribute__((ext_vector_type(8))) short short8;

#define GLOAD_LDS16(g, l)                                                        \
  __builtin_amdgcn_global_load_lds(                                              \
      (const __attribute__((address_space(1))) void*)(g),                        \
      (__attribute__((address_space(3))) void*)(l), 16, 0, 0)

// ---------------- gamma = mean(|W|): deterministic 2-stage reduction ----------
__global__ void absum_partial(const float* __restrict__ W,
                              float* __restrict__ partials, int n) {
  int tid = blockIdx.x * blockDim.x + threadIdx.x;
  int stride = gridDim.x * blockDim.x;
  const f32x4* W4 = (const f32x4*)W;
  int n4 = n >> 2;
  float s = 0.f;
  for (int i = tid; i < n4; i += stride) {
    f32x4 v = W4[i];
    s += fabsf(v[0]) + fabsf(v[1]) + fabsf(v[2]) + fabsf(v[3]);
  }
#pragma unroll
  for (int off = 32; off > 0; off >>= 1) s += __shfl_down(s, off, 64);
  __shared__ float wsum[4];
  if ((threadIdx.x & 63) == 0) wsum[threadIdx.x >> 6] = s;
  __syncthreads();
  if (threadIdx.x == 0)
    partials[blockIdx.x] = wsum[0] + wsum[1] + wsum[2] + wsum[3];
}

__global__ void gamma_finalize(const float* __restrict__ partials,
                               float* __restrict__ gamma, float inv_n) {
  __shared__ float sm[256];
  int t = threadIdx.x;
  sm[t] = partials[t] + partials[t + 256] + partials[t + 512] + partials[t + 768];
  __syncthreads();
  for (int off = 128; off > 0; off >>= 1) {
    if (t < off) sm[t] += sm[t + off];
    __syncthreads();
  }
  if (t == 0) gamma[0] = sm[0] * inv_n;
}

// ---------------- W -> ternary bf16 (exact {-1,0,1}) --------------------------
__global__ void quantize_w(const float* __restrict__ W,
                           unsigned short* __restrict__ Wq,
                           const float* __restrict__ gamma_p, int n) {
  float g = gamma_p[0];
  float safe = (g == 0.f) ? 1.f : g;
  int tid = blockIdx.x * blockDim.x + threadIdx.x;
  int stride = gridDim.x * blockDim.x;
  const f32x4* W4 = (const f32x4*)W;
  int n4 = n >> 2;
  for (int i = tid; i < n4; i += stride) {
    f32x4 v = W4[i];
    ushort4 q;
    float t0 = rintf(v[0] / safe);
    float t1 = rintf(v[1] / safe);
    float t2 = rintf(v[2] / safe);
    float t3 = rintf(v[3] / safe);
    q.x = (t0 >= 0.5f) ? 0x3F80u : (t0 <= -0.5f ? 0xBF80u : 0u);
    q.y = (t1 >= 0.5f) ? 0x3F80u : (t1 <= -0.5f ? 0xBF80u : 0u);
    q.z = (t2 >= 0.5f) ? 0x3F80u : (t2 <= -0.5f ? 0xBF80u : 0u);
    q.w = (t3 >= 0.5f) ? 0x3F80u : (t3 <= -0.5f ? 0xBF80u : 0u);
    ((ushort4*)Wq)[i] = q;
  }
}

// ---------------- x fp32 -> bf16 (RTN-even) -----------------------------------
__global__ void convert_x(const float* __restrict__ X,
                          unsigned short* __restrict__ Xb, int n) {
  int tid = blockIdx.x * blockDim.x + threadIdx.x;
  int stride = gridDim.x * blockDim.x;
  const f32x4* X4 = (const f32x4*)X;
  int n4 = n >> 2;
  for (int i = tid; i < n4; i += stride) {
    f32x4 v = X4[i];
    ushort4 o;
    unsigned u0 = __float_as_uint(v[0]);
    unsigned u1 = __float_as_uint(v[1]);
    unsigned u2 = __float_as_uint(v[2]);
    unsigned u3 = __float_as_uint(v[3]);
    o.x = (unsigned short)((u0 + 0x7FFFu + ((u0 >> 16) & 1u)) >> 16);
    o.y = (unsigned short)((u1 + 0x7FFFu + ((u1 >> 16) & 1u)) >> 16);
    o.z = (unsigned short)((u2 + 0x7FFFu + ((u2 >> 16) & 1u)) >> 16);
    o.w = (unsigned short)((u3 + 0x7FFFu + ((u3 >> 16) & 1u)) >> 16);
    ((ushort4*)Xb)[i] = o;
  }
}

// ------- 256x256 bf16 GEMM: register-double-buffered fragments, 1 BAR/tile ----
// 512 threads = 8 waves (2Mx4N), wave output 128x64 (8x4 frags 16x16x32).
// K-tile 32, ring-4 LDS slots ([256][32] bf16 = 16KB each; A+B = 128KiB).
// Tile p: enter with (bf,af0) of tile p in regs (prefetched tile p-1).
//   STAGE(p+3); issue af1_p (4 ds_read); lgkm(4) [waits prefetch-8]; SB0;
//   16 MFMA h0 (no operand wait); issue prefetch (bf,af0) of p+1 (8 ds_read);
//   lgkm(8) [af1 done, drained under h0]; SB0; 16 MFMA h1 (prefetch-8 drains
//   under h1); VMC(4); BAR.  All LDS reads overlap MFMA; one barrier/tile.
// vmcnt ledger: tile q staged at q-3, complete by VMC(4) at end of q-2 (only
// newest stage outstanding), published by that BAR; first read of tile q is
// the prefetch during tile q-1. Tail: VMC(0) at tile 125 publishes tile 127
// before 126's prefetch. Waves spread <=1 tile (single barrier) -> stage slot
// (p+3)&3 never collides with slots being read (p&3, (p+1)&3).
// T2 swizzle (both-sides, rule #21): LDS[row][q16B] = global[row][q ^
// ((row>>1)&3)]; staging permutes the GLOBAL chunk (LDS dest linear); reads
// fold the same XOR into the base (row bits[2:1] == lr bits[2:1] always).
__global__ __launch_bounds__(512, 2)
void gemm256_rdb(const unsigned short* __restrict__ A,
                 const unsigned short* __restrict__ Bq,
                 float* __restrict__ C,
                 const float* __restrict__ gamma_p, int M, int N) {
  __shared__ __align__(16) unsigned short Abuf[4][256][32];  // 64 KiB
  __shared__ __align__(16) unsigned short Bbuf[4][256][32];  // 64 KiB

  int ntN = N >> 8;
  int bid = blockIdx.x;
  int swz = (bid & 7) * (gridDim.x >> 3) + (bid >> 3);  // nwg % 8 == 0
  int tm = swz / ntN, tn = swz % ntN;

  int t = threadIdx.x;
  int lane = t & 63;
  int wid = t >> 6;
  int wr = wid >> 2, wc = wid & 3;   // 2 x 4 wave grid
  int lr = lane & 15;
  int lks = (((lane >> 4) ^ ((lr >> 1) & 3)) << 3);  // swizzled k-chunk (shorts)

  const char* aG = (const char*)(A + (size_t)tm * 256 * K_DIM);
  const char* bG = (const char*)(Bq + (size_t)tn * 256 * K_DIM);

  // staging: thread t -> LDS 16B chunk (row = t>>2, chunk = t&3);
  // global source chunk = (t&3) ^ ((row>>1)&3)
  int srow = t >> 2;
  int schunk = (t & 3) ^ ((t >> 3) & 3);
  const char* aSg = aG + (size_t)srow * (K_DIM * 2) + (schunk << 4);
  const char* bSg = bG + (size_t)srow * (K_DIM * 2) + (schunk << 4);
  char* aSl = (char*)Abuf + t * 16;
  char* bSl = (char*)Bbuf + t * 16;

  const unsigned short* aRd = &Abuf[0][0][0] + (wr * 128 + lr) * 32 + lks;
  const unsigned short* bRd = &Bbuf[0][0][0] + (wc * 64 + lr) * 32 + lks;

  f32x4 acc[8][4];
#pragma unroll
  for (int m = 0; m < 8; ++m)
#pragma unroll
    for (int n = 0; n < 4; ++n) acc[m][n] = (f32x4)(0.f);

#define STAGE_A(jj)                                                            \
  { GLOAD_LDS16(aSg + (size_t)(jj) * 64, aSl + ((jj) & 3) * 16384);            \
    GLOAD_LDS16(aSg + (size_t)(jj) * 64 + (size_t)128 * K_DIM * 2,             \
                aSl + ((jj) & 3) * 16384 + 8192); }
#define STAGE_B(jj)                                                            \
  { GLOAD_LDS16(bSg + (size_t)(jj) * 64, bSl + ((jj) & 3) * 16384);            \
    GLOAD_LDS16(bSg + (size_t)(jj) * 64 + (size_t)128 * K_DIM * 2,             \
                bSl + ((jj) & 3) * 16384 + 8192); }
#define BAR() __builtin_amdgcn_s_barrier()
#define VMC(NN) asm volatile("s_waitcnt vmcnt(" #NN ")" ::: "memory")
#define SB0() __builtin_amdgcn_sched_barrier(0)

  // TILE_BODY(SLOT: this tile's LDS slot (const), JSTG: tile to stage,
  //           DO_STG, DO_PRE, NSLOT: next tile's slot, BF_C/AF0_C: current
  //           frag bank, BF_N/AF0_N: bank to prefetch into, VMEND, DO_BAR)
#define TILE_BODY(SLOT, JSTG, DO_STG, DO_PRE, NSLOT, BF_C, AF0_C, BF_N, AF0_N, \
                  VMEND, DO_BAR)                                               \
  {                                                                            \
    if (DO_STG) { STAGE_A(JSTG); STAGE_B(JSTG); }                              \
    _Pragma("unroll") for (int m = 0; m < 4; ++m)                              \
      af1[m] = *(const short8*)(aRd + (SLOT) * 8192 + 2048 + m * 512);         \
    asm volatile("s_waitcnt lgkmcnt(4)" ::: "memory");                         \
    SB0();                                                                     \
    __builtin_amdgcn_s_setprio(1);                                             \
    _Pragma("unroll") for (int m = 0; m < 4; ++m)                              \
      _Pragma("unroll") for (int n = 0; n < 4; ++n)                            \
        acc[m][n] = __builtin_amdgcn_mfma_f32_16x16x32_bf16(                   \
            AF0_C[m], BF_C[n], acc[m][n], 0, 0, 0);                            \
    __builtin_amdgcn_s_setprio(0);                                             \
    if (DO_PRE) {                                                              \
      _Pragma("unroll") for (int n = 0; n < 4; ++n)                            \
        BF_N[n] = *(const short8*)(bRd + (NSLOT) * 8192 + n * 512);            \
      _Pragma("unroll") for (int m = 0; m < 4; ++m)                            \
        AF0_N[m] = *(const short8*)(aRd + (NSLOT) * 8192 + m * 512);           \
      asm volatile("s_waitcnt lgkmcnt(8)" ::: "memory");                       \
    } else {                                                                   \
      asm volatile("s_waitcnt lgkmcnt(0)" ::: "memory");                       \
    }                                                                          \
    SB0();                                                                     \
    __builtin_amdgcn_s_setprio(1);                                             \
    _Pragma("unroll") for (int m = 0; m < 4; ++m)                              \
      _Pragma("unroll") for (int n = 0; n < 4; ++n)                            \
        acc[4 + m][n] = __builtin_amdgcn_mfma_f32_16x16x32_bf16(               \
            af1[m], BF_C[n], acc[4 + m][n], 0, 0, 0);                          \
    __builtin_amdgcn_s_setprio(0);                                             \
    VMEND;                                                                     \
    if (DO_BAR) BAR();                                                         \
  }

  // prologue: stage tiles 0,1,2; tiles 0,1 complete (tile 2 in flight);
  // preload tile 0 fragments into the E bank.
  STAGE_A(0); STAGE_B(0); STAGE_A(1); STAGE_B(1); STAGE_A(2); STAGE_B(2);
  VMC(4);
  BAR();

  short8 bfE[4], af0E[4], bfO[4], af0O[4], af1[4];
#pragma unroll
  for (int n = 0; n < 4; ++n) bfE[n] = *(const short8*)(bRd + n * 512);
#pragma unroll
  for (int m = 0; m < 4; ++m) af0E[m] = *(const short8*)(aRd + m * 512);

  // steady state: tiles 0..123, 4 per iteration (slots 0..3, banks E,O,E,O)
  for (int i = 0; i < 31; ++i) {
    int p = i << 2;
    TILE_BODY(0, p + 3, 1, 1, 1, bfE, af0E, bfO, af0O, VMC(4), 1);
    TILE_BODY(1, p + 4, 1, 1, 2, bfO, af0O, bfE, af0E, VMC(4), 1);
    TILE_BODY(2, p + 5, 1, 1, 3, bfE, af0E, bfO, af0O, VMC(4), 1);
    TILE_BODY(3, p + 6, 1, 1, 0, bfO, af0O, bfE, af0E, VMC(4), 1);
  }
  // tail: tiles 124 (stage 127), 125 (VMC(0) publishes tile 127), 126, 127
  TILE_BODY(0, 127, 1, 1, 1, bfE, af0E, bfO, af0O, VMC(4), 1);
  TILE_BODY(1, 0, 0, 1, 2, bfO, af0O, bfE, af0E, VMC(0), 1);
  TILE_BODY(2, 0, 0, 1, 3, bfE, af0E, bfO, af0O, (void)0, 1);
  TILE_BODY(3, 0, 0, 0, 0, bfO, af0O, bfE, af0E, (void)0, 0);

  float g = gamma_p[0];
  int crow = (lane >> 4) << 2;   // C/D: col = lane&15, row = (lane>>4)*4 + reg
  size_t row0 = (size_t)tm * 256 + wr * 128 + crow;
  int col0 = tn * 256 + wc * 64 + lr;
#pragma unroll
  for (int m = 0; m < 8; ++m) {
#pragma unroll
    for (int j = 0; j < 4; ++j) {
      float* cp = C + (row0 + m * 16 + j) * (size_t)N + col0;
#pragma unroll
      for (int n = 0; n < 4; ++n) cp[n * 16] = acc[m][n][j] * g;
    }
  }
#undef STAGE_A
#undef STAGE_B
#undef BAR
#undef VMC
#undef SB0
#undef TILE_BODY
}

// ---------------- naive fallback (only if ws too small / odd shapes) ----------
__global__ void naive_bitlinear(const float* __restrict__ X,
                                const float* __restrict__ W,
                                float* __restrict__ out,
                                const float* __restrict__ gamma_p, int M, int N) {
  int col = blockIdx.x * blockDim.x + threadIdx.x;
  int row = blockIdx.y;
  if (col >= N || row >= M) return;
  float g = gamma_p[0];
  float safe = (g == 0.f) ? 1.f : g;
  const float* x = X + (size_t)row * K_DIM;
  const float* w = W + (size_t)col * K_DIM;
  float s = 0.f;
  for (int k = 0; k < K_DIM; ++k) {
    float qv = fminf(fmaxf(rintf(w[k] / safe), -1.f), 1.f);
    s += x[k] * qv;
  }
  out[(size_t)row * N + col] = s * g;
}

extern "C" void kernel_launch(void* const* d_in, const int* in_sizes, int n_in,
                              void* d_out, int out_size, void* d_ws,
                              size_t ws_size, hipStream_t stream) {
  const float* x = (const float*)d_in[0];
  const float* w = (const float*)d_in[1];
  float* out = (float*)d_out;
  int xn = in_sizes[0];   // B*S*D_IN = 33554432
  int wn = in_sizes[1];   // D_OUT*D_IN = 16777216
  int M = xn / K_DIM;     // 8192
  int N = wn / K_DIM;     // 4096

  char* ws = (char*)d_ws;
  float* partials = (float*)ws;                       // 1024 floats
  float* gamma = (float*)(ws + 4096);                 // 1 float
  unsigned short* Wq = (unsigned short*)(ws + 8192);  // N*K bf16
  unsigned short* Xb = Wq + (size_t)wn;               // M*K bf16
  size_t need = 8192 + (size_t)wn * 2 + (size_t)xn * 2;

  absum_partial<<<1024, 256, 0, stream>>>(w, partials, wn);
  gamma_finalize<<<1, 256, 0, stream>>>(partials, gamma, 1.0f / (float)wn);

  if (ws_size >= need && (M & 255) == 0 && (N & 255) == 0) {
    quantize_w<<<2048, 256, 0, stream>>>(w, Wq, gamma, wn);
    convert_x<<<2048, 256, 0, stream>>>(x, Xb, xn);
    int nwg = (M >> 8) * (N >> 8);   // 32 * 16 = 512
    gemm256_rdb<<<nwg, 512, 0, stream>>>(Xb, Wq, out, gamma, M, N);
  } else {
    dim3 grid((N + 255) / 256, M);
    naive_bitlinear<<<grid, 256, 0, stream>>>(x, w, out, gamma, M, N);
  }
}

// Round 6
// 294.441 us; speedup vs baseline: 1.2218x; 1.0322x over previous
//
#include <hip/hip_runtime.h>
#include <hip/hip_bf16.h>
#include <stdint.h>

#define K_DIM 4096
#define NT64  (K_DIM / 64)   // 64 K-tiles of BK=64

typedef __attribute__((ext_vector_type(4))) float f32x4;
typedef __attribute__((ext_vector_type(8))) short short8;

#define GLOAD_LDS16(g, l)                                                        \
  __builtin_amdgcn_global_load_lds(                                              \
      (const __attribute__((address_space(1))) void*)(g),                        \
      (__attribute__((address_space(3))) void*)(l), 16, 0, 0)

// ---------------- gamma = mean(|W|): deterministic 2-stage reduction ----------
__global__ void absum_partial(const float* __restrict__ W,
                              float* __restrict__ partials, int n) {
  int tid = blockIdx.x * blockDim.x + threadIdx.x;
  int stride = gridDim.x * blockDim.x;
  const f32x4* W4 = (const f32x4*)W;
  int n4 = n >> 2;
  float s = 0.f;
  for (int i = tid; i < n4; i += stride) {
    f32x4 v = W4[i];
    s += fabsf(v[0]) + fabsf(v[1]) + fabsf(v[2]) + fabsf(v[3]);
  }
#pragma unroll
  for (int off = 32; off > 0; off >>= 1) s += __shfl_down(s, off, 64);
  __shared__ float wsum[4];
  if ((threadIdx.x & 63) == 0) wsum[threadIdx.x >> 6] = s;
  __syncthreads();
  if (threadIdx.x == 0)
    partials[blockIdx.x] = wsum[0] + wsum[1] + wsum[2] + wsum[3];
}

__global__ void gamma_finalize(const float* __restrict__ partials,
                               float* __restrict__ gamma, float inv_n) {
  __shared__ float sm[256];
  int t = threadIdx.x;
  sm[t] = partials[t] + partials[t + 256] + partials[t + 512] + partials[t + 768];
  __syncthreads();
  for (int off = 128; off > 0; off >>= 1) {
    if (t < off) sm[t] += sm[t + off];
    __syncthreads();
  }
  if (t == 0) gamma[0] = sm[0] * inv_n;
}

// ---------------- W -> ternary bf16 (exact {-1,0,1}) --------------------------
__global__ void quantize_w(const float* __restrict__ W,
                           unsigned short* __restrict__ Wq,
                           const float* __restrict__ gamma_p, int n) {
  float g = gamma_p[0];
  float safe = (g == 0.f) ? 1.f : g;
  int tid = blockIdx.x * blockDim.x + threadIdx.x;
  int stride = gridDim.x * blockDim.x;
  const f32x4* W4 = (const f32x4*)W;
  int n4 = n >> 2;
  for (int i = tid; i < n4; i += stride) {
    f32x4 v = W4[i];
    ushort4 q;
    float t0 = rintf(v[0] / safe);
    float t1 = rintf(v[1] / safe);
    float t2 = rintf(v[2] / safe);
    float t3 = rintf(v[3] / safe);
    q.x = (t0 >= 0.5f) ? 0x3F80u : (t0 <= -0.5f ? 0xBF80u : 0u);
    q.y = (t1 >= 0.5f) ? 0x3F80u : (t1 <= -0.5f ? 0xBF80u : 0u);
    q.z = (t2 >= 0.5f) ? 0x3F80u : (t2 <= -0.5f ? 0xBF80u : 0u);
    q.w = (t3 >= 0.5f) ? 0x3F80u : (t3 <= -0.5f ? 0xBF80u : 0u);
    ((ushort4*)Wq)[i] = q;
  }
}

// ---------------- x fp32 -> bf16 (RTN-even) -----------------------------------
__global__ void convert_x(const float* __restrict__ X,
                          unsigned short* __restrict__ Xb, int n) {
  int tid = blockIdx.x * blockDim.x + threadIdx.x;
  int stride = gridDim.x * blockDim.x;
  const f32x4* X4 = (const f32x4*)X;
  int n4 = n >> 2;
  for (int i = tid; i < n4; i += stride) {
    f32x4 v = X4[i];
    ushort4 o;
    unsigned u0 = __float_as_uint(v[0]);
    unsigned u1 = __float_as_uint(v[1]);
    unsigned u2 = __float_as_uint(v[2]);
    unsigned u3 = __float_as_uint(v[3]);
    o.x = (unsigned short)((u0 + 0x7FFFu + ((u0 >> 16) & 1u)) >> 16);
    o.y = (unsigned short)((u1 + 0x7FFFu + ((u1 >> 16) & 1u)) >> 16);
    o.z = (unsigned short)((u2 + 0x7FFFu + ((u2 >> 16) & 1u)) >> 16);
    o.w = (unsigned short)((u3 + 0x7FFFu + ((u3 >> 16) & 1u)) >> 16);
    ((ushort4*)Xb)[i] = o;
  }
}

// ------- 256x256 bf16 GEMM: BK=64 dbuf-2, 1 barrier + 1 vmcnt per K=64 --------
// 512 threads = 8 waves (2Mx4N), wave output 128x64 (8x4 frags 16x16x32).
// LDS: [2 slots][256 rows][64 k] bf16 per matrix = 32KB/slot, A+B = 128KiB.
// Tile p (slot s=p&1): stage tile p+1 -> slot s^1 (8 gload_lds); issue 16
// ds_read (A-top k0, B k0, A-top k1, B k1; SB0-pinned groups); lgkm(8) ->
// 16 MFMA (at0xb0); issue 8 ds_read (A-bot k0,k1); lgkm(8) -> 16 MFMA
// (at1xb1); lgkm(4) -> 16 MFMA (ab0xb0); lgkm(0) -> 16 MFMA (ab1xb1);
// vmcnt(0); BAR. DS ops complete in-order per wave -> counted lgkm maps to
// frag groups; SB0 after each wait (rule 18) and between issue groups pins
// compiler order. WAR audit: reads of slot s^1 all complete (lgkm(0) gates
// block4) before the end-BAR of tile p-1; stage into s^1 issues after it.
// Swizzle (both-sides, rule 21): LDS[row][c16B] = global[row][c ^ (row&7)];
// staging permutes GLOBAL chunk (LDS dest linear); reads fold the XOR into
// the base (row bits[2:0] == lr bits[2:0] for every fragment row). Lane->
// bank audit: 32B/bank/wave for every b128 group = balanced, conflict-free.
__global__ __launch_bounds__(512, 2)
void gemm256_k64(const unsigned short* __restrict__ A,
                 const unsigned short* __restrict__ Bq,
                 float* __restrict__ C,
                 const float* __restrict__ gamma_p, int M, int N) {
  __shared__ __align__(16) unsigned short Abuf[2][256][64];  // 64 KiB
  __shared__ __align__(16) unsigned short Bbuf[2][256][64];  // 64 KiB

  int ntN = N >> 8;
  int bid = blockIdx.x;
  int swz = (bid & 7) * (gridDim.x >> 3) + (bid >> 3);  // nwg % 8 == 0
  int tm = swz / ntN, tn = swz % ntN;

  int t = threadIdx.x;
  int lane = t & 63;
  int wid = t >> 6;
  int wr = wid >> 2, wc = wid & 3;   // 2 x 4 wave grid
  int lr = lane & 15;
  int sc0 = (lane >> 4) ^ (lr & 7);  // swizzled chunk for kstep0 (chunks 0..7)

  const char* aG = (const char*)(A + (size_t)tm * 256 * K_DIM);
  const char* bG = (const char*)(Bq + (size_t)tn * 256 * K_DIM);

  // staging: thread t -> LDS chunk (row = t>>3, c = t&7), rows +64*i;
  // global source chunk = c ^ (row&7)
  int srow = t >> 3;
  int schunk = (t & 7) ^ ((t >> 3) & 7);
  const char* aSg = aG + (size_t)srow * (K_DIM * 2) + (schunk << 4);
  const char* bSg = bG + (size_t)srow * (K_DIM * 2) + (schunk << 4);
  char* aSl = (char*)Abuf + t * 16;
  char* bSl = (char*)Bbuf + t * 16;

  const unsigned short* aRd0 = &Abuf[0][0][0] + (wr * 128 + lr) * 64 + sc0 * 8;
  const unsigned short* aRd1 = &Abuf[0][0][0] + (wr * 128 + lr) * 64 + (sc0 ^ 4) * 8;
  const unsigned short* bRd0 = &Bbuf[0][0][0] + (wc * 64 + lr) * 64 + sc0 * 8;
  const unsigned short* bRd1 = &Bbuf[0][0][0] + (wc * 64 + lr) * 64 + (sc0 ^ 4) * 8;

  f32x4 acc[8][4];
#pragma unroll
  for (int m = 0; m < 8; ++m)
#pragma unroll
    for (int n = 0; n < 4; ++n) acc[m][n] = (f32x4)(0.f);

#define STAGE_A(jj, S)                                                         \
  { _Pragma("unroll") for (int i = 0; i < 4; ++i)                              \
      GLOAD_LDS16(aSg + (size_t)(jj) * 128 + (size_t)i * (64 * K_DIM * 2),     \
                  aSl + (S) * 32768 + i * 8192); }
#define STAGE_B(jj, S)                                                         \
  { _Pragma("unroll") for (int i = 0; i < 4; ++i)                              \
      GLOAD_LDS16(bSg + (size_t)(jj) * 128 + (size_t)i * (64 * K_DIM * 2),     \
                  bSl + (S) * 32768 + i * 8192); }
#define BAR() __builtin_amdgcn_s_barrier()
#define VMC0() asm volatile("s_waitcnt vmcnt(0)" ::: "memory")
#define LGKM(NN) asm volatile("s_waitcnt lgkmcnt(" #NN ")" ::: "memory")
#define SB0() __builtin_amdgcn_sched_barrier(0)
#define MFMA16(AF, ACCROW)                                                     \
  { _Pragma("unroll") for (int m = 0; m < 4; ++m)                              \
      _Pragma("unroll") for (int n = 0; n < 4; ++n)                            \
        acc[(ACCROW) + m][n] = __builtin_amdgcn_mfma_f32_16x16x32_bf16(        \
            AF[m], ((ACCROW) ? ((m & 0) ? b0 : b0) : b0)[n],                   \
            acc[(ACCROW) + m][n], 0, 0, 0); }

  // TILE(S: slot const, JSTG: tile to stage, DO_STG, DO_END: vmcnt+bar)
#define TILE(S, JSTG, DO_STG, DO_END)                                          \
  {                                                                            \
    if (DO_STG) { STAGE_A(JSTG, (S) ^ 1); STAGE_B(JSTG, (S) ^ 1); }            \
    _Pragma("unroll") for (int m = 0; m < 4; ++m)                              \
      at0[m] = *(const short8*)(aRd0 + (S) * 16384 + m * 1024);                \
    _Pragma("unroll") for (int n = 0; n < 4; ++n)                              \
      b0[n] = *(const short8*)(bRd0 + (S) * 16384 + n * 1024);                 \
    SB0();                                                                     \
    _Pragma("unroll") for (int m = 0; m < 4; ++m)                              \
      at1[m] = *(const short8*)(aRd1 + (S) * 16384 + m * 1024);                \
    _Pragma("unroll") for (int n = 0; n < 4; ++n)                              \
      b1[n] = *(const short8*)(bRd1 + (S) * 16384 + n * 1024);                 \
    SB0();                                                                     \
    LGKM(8); SB0();                                                            \
    __builtin_amdgcn_s_setprio(1);                                             \
    _Pragma("unroll") for (int m = 0; m < 4; ++m)                              \
      _Pragma("unroll") for (int n = 0; n < 4; ++n)                            \
        acc[m][n] = __builtin_amdgcn_mfma_f32_16x16x32_bf16(                   \
            at0[m], b0[n], acc[m][n], 0, 0, 0);                                \
    __builtin_amdgcn_s_setprio(0);                                             \
    _Pragma("unroll") for (int m = 0; m < 4; ++m)                              \
      ab0[m] = *(const short8*)(aRd0 + (S) * 16384 + 4096 + m * 1024);         \
    _Pragma("unroll") for (int m = 0; m < 4; ++m)                              \
      ab1[m] = *(const short8*)(aRd1 + (S) * 16384 + 4096 + m * 1024);         \
    SB0();                                                                     \
    LGKM(8); SB0();                                                            \
    __builtin_amdgcn_s_setprio(1);                                             \
    _Pragma("unroll") for (int m = 0; m < 4; ++m)                              \
      _Pragma("unroll") for (int n = 0; n < 4; ++n)                            \
        acc[m][n] = __builtin_amdgcn_mfma_f32_16x16x32_bf16(                   \
            at1[m], b1[n], acc[m][n], 0, 0, 0);                                \
    __builtin_amdgcn_s_setprio(0);                                             \
    LGKM(4); SB0();                                                            \
    __builtin_amdgcn_s_setprio(1);                                             \
    _Pragma("unroll") for (int m = 0; m < 4; ++m)                              \
      _Pragma("unroll") for (int n = 0; n < 4; ++n)                            \
        acc[4 + m][n] = __builtin_amdgcn_mfma_f32_16x16x32_bf16(               \
            ab0[m], b0[n], acc[4 + m][n], 0, 0, 0);                            \
    __builtin_amdgcn_s_setprio(0);                                             \
    LGKM(0); SB0();                                                            \
    __builtin_amdgcn_s_setprio(1);                                             \
    _Pragma("unroll") for (int m = 0; m < 4; ++m)                              \
      _Pragma("unroll") for (int n = 0; n < 4; ++n)                            \
        acc[4 + m][n] = __builtin_amdgcn_mfma_f32_16x16x32_bf16(               \
            ab1[m], b1[n], acc[4 + m][n], 0, 0, 0);                            \
    __builtin_amdgcn_s_setprio(0);                                             \
    if (DO_END) { VMC0(); BAR(); }                                             \
  }

  // prologue: stage tile 0 -> slot 0, drain, publish
  STAGE_A(0, 0); STAGE_B(0, 0);
  VMC0();
  BAR();

  short8 at0[4], at1[4], ab0[4], ab1[4], b0[4], b1[4];
  // tiles 0..61 (31 x 2), then 62 (stage 63), then 63 (no stage)
  for (int i = 0; i < 31; ++i) {
    int p = i << 1;
    TILE(0, p + 1, 1, 1);
    TILE(1, p + 2, 1, 1);
  }
  TILE(0, 63, 1, 1);
  TILE(1, 0, 0, 0);

  float g = gamma_p[0];
  int crow = (lane >> 4) << 2;   // C/D: col = lane&15, row = (lane>>4)*4 + reg
  size_t row0 = (size_t)tm * 256 + wr * 128 + crow;
  int col0 = tn * 256 + wc * 64 + lr;
#pragma unroll
  for (int m = 0; m < 8; ++m) {
#pragma unroll
    for (int j = 0; j < 4; ++j) {
      float* cp = C + (row0 + m * 16 + j) * (size_t)N + col0;
#pragma unroll
      for (int n = 0; n < 4; ++n) cp[n * 16] = acc[m][n][j] * g;
    }
  }
#undef STAGE_A
#undef STAGE_B
#undef BAR
#undef VMC0
#undef LGKM
#undef SB0
#undef MFMA16
#undef TILE
}

// ---------------- naive fallback (only if ws too small / odd shapes) ----------
__global__ void naive_bitlinear(const float* __restrict__ X,
                                const float* __restrict__ W,
                                float* __restrict__ out,
                                const float* __restrict__ gamma_p, int M, int N) {
  int col = blockIdx.x * blockDim.x + threadIdx.x;
  int row = blockIdx.y;
  if (col >= N || row >= M) return;
  float g = gamma_p[0];
  float safe = (g == 0.f) ? 1.f : g;
  const float* x = X + (size_t)row * K_DIM;
  const float* w = W + (size_t)col * K_DIM;
  float s = 0.f;
  for (int k = 0; k < K_DIM; ++k) {
    float qv = fminf(fmaxf(rintf(w[k] / safe), -1.f), 1.f);
    s += x[k] * qv;
  }
  out[(size_t)row * N + col] = s * g;
}

extern "C" void kernel_launch(void* const* d_in, const int* in_sizes, int n_in,
                              void* d_out, int out_size, void* d_ws,
                              size_t ws_size, hipStream_t stream) {
  const float* x = (const float*)d_in[0];
  const float* w = (const float*)d_in[1];
  float* out = (float*)d_out;
  int xn = in_sizes[0];   // B*S*D_IN = 33554432
  int wn = in_sizes[1];   // D_OUT*D_IN = 16777216
  int M = xn / K_DIM;     // 8192
  int N = wn / K_DIM;     // 4096

  char* ws = (char*)d_ws;
  float* partials = (float*)ws;                       // 1024 floats
  float* gamma = (float*)(ws + 4096);                 // 1 float
  unsigned short* Wq = (unsigned short*)(ws + 8192);  // N*K bf16
  unsigned short* Xb = Wq + (size_t)wn;               // M*K bf16
  size_t need = 8192 + (size_t)wn * 2 + (size_t)xn * 2;

  absum_partial<<<1024, 256, 0, stream>>>(w, partials, wn);
  gamma_finalize<<<1, 256, 0, stream>>>(partials, gamma, 1.0f / (float)wn);

  if (ws_size >= need && (M & 255) == 0 && (N & 255) == 0) {
    quantize_w<<<2048, 256, 0, stream>>>(w, Wq, gamma, wn);
    convert_x<<<2048, 256, 0, stream>>>(x, Xb, xn);
    int nwg = (M >> 8) * (N >> 8);   // 32 * 16 = 512
    gemm256_k64<<<nwg, 512, 0, stream>>>(Xb, Wq, out, gamma, M, N);
  } else {
    dim3 grid((N + 255) / 256, M);
    naive_bitlinear<<<grid, 256, 0, stream>>>(x, w, out, gamma, M, N);
  }
}

// Round 7
// 205.730 us; speedup vs baseline: 1.7486x; 1.4312x over previous
//
#include <hip/hip_runtime.h>
#include <hip/hip_bf16.h>
#include <stdint.h>

#define K_DIM 4096

typedef __attribute__((ext_vector_type(4))) float f32x4;
typedef __attribute__((ext_vector_type(4))) int i32x4;

#define GLOAD_LDS16(g, l)                                                        \
  __builtin_amdgcn_global_load_lds(                                              \
      (const __attribute__((address_space(1))) void*)(g),                        \
      (__attribute__((address_space(3))) void*)(l), 16, 0, 0)

// ---------------- gamma = mean(|W|): deterministic 2-stage reduction ----------
__global__ void absum_partial(const float* __restrict__ W,
                              float* __restrict__ partials, int n) {
  int tid = blockIdx.x * blockDim.x + threadIdx.x;
  int stride = gridDim.x * blockDim.x;
  const f32x4* W4 = (const f32x4*)W;
  int n4 = n >> 2;
  float s = 0.f;
  for (int i = tid; i < n4; i += stride) {
    f32x4 v = W4[i];
    s += fabsf(v[0]) + fabsf(v[1]) + fabsf(v[2]) + fabsf(v[3]);
  }
#pragma unroll
  for (int off = 32; off > 0; off >>= 1) s += __shfl_down(s, off, 64);
  __shared__ float wsum[4];
  if ((threadIdx.x & 63) == 0) wsum[threadIdx.x >> 6] = s;
  __syncthreads();
  if (threadIdx.x == 0)
    partials[blockIdx.x] = wsum[0] + wsum[1] + wsum[2] + wsum[3];
}

__global__ void gamma_finalize(const float* __restrict__ partials,
                               float* __restrict__ gamma, float inv_n) {
  __shared__ float sm[256];
  int t = threadIdx.x;
  sm[t] = partials[t] + partials[t + 256] + partials[t + 512] + partials[t + 768];
  __syncthreads();
  for (int off = 128; off > 0; off >>= 1) {
    if (t < off) sm[t] += sm[t + off];
    __syncthreads();
  }
  if (t == 0) gamma[0] = sm[0] * inv_n;
}

// ---------------- W -> ternary i8 (exact {-1,0,1}) ----------------------------
__global__ void quantize_w_i8(const float* __restrict__ W,
                              signed char* __restrict__ Wq,
                              const float* __restrict__ gamma_p, int n) {
  float g = gamma_p[0];
  float safe = (g == 0.f) ? 1.f : g;
  int tid = blockIdx.x * blockDim.x + threadIdx.x;
  int stride = gridDim.x * blockDim.x;
  const f32x4* W4 = (const f32x4*)W;
  int n4 = n >> 2;
  int* out = (int*)Wq;
  for (int i = tid; i < n4; i += stride) {
    f32x4 v = W4[i];
    int b0, b1, b2, b3;
    float t0 = rintf(v[0] / safe);
    float t1 = rintf(v[1] / safe);
    float t2 = rintf(v[2] / safe);
    float t3 = rintf(v[3] / safe);
    b0 = (t0 >= 0.5f) ? 1 : (t0 <= -0.5f ? -1 : 0);
    b1 = (t1 >= 0.5f) ? 1 : (t1 <= -0.5f ? -1 : 0);
    b2 = (t2 >= 0.5f) ? 1 : (t2 <= -0.5f ? -1 : 0);
    b3 = (t3 >= 0.5f) ? 1 : (t3 <= -0.5f ? -1 : 0);
    out[i] = (b0 & 255) | ((b1 & 255) << 8) | ((b2 & 255) << 16) |
             ((b3 & 255) << 24);
  }
}

// -------- x fp32 -> i8 with per-row scale: x_q = rint(127*x/rowmax) -----------
__global__ __launch_bounds__(256)
void quant_x_i8(const float* __restrict__ X, signed char* __restrict__ Xq,
                float* __restrict__ xscale) {
  int row = blockIdx.x;
  int t = threadIdx.x;
  const f32x4* xr = (const f32x4*)(X + (size_t)row * K_DIM);
  f32x4 v0 = xr[t], v1 = xr[t + 256], v2 = xr[t + 512], v3 = xr[t + 768];
  float mx = 0.f;
#define AMAX4(V)                                                               \
  mx = fmaxf(mx, fmaxf(fmaxf(fabsf(V[0]), fabsf(V[1])),                        \
                       fmaxf(fabsf(V[2]), fabsf(V[3]))));
  AMAX4(v0) AMAX4(v1) AMAX4(v2) AMAX4(v3)
#undef AMAX4
#pragma unroll
  for (int off = 32; off > 0; off >>= 1) mx = fmaxf(mx, __shfl_down(mx, off, 64));
  __shared__ float wmx[4];
  if ((t & 63) == 0) wmx[t >> 6] = mx;
  __syncthreads();
  float rmax = fmaxf(fmaxf(wmx[0], wmx[1]), fmaxf(wmx[2], wmx[3]));
  float inv = (rmax > 0.f) ? 127.0f / rmax : 0.f;
  if (t == 0) xscale[row] = (rmax > 0.f) ? rmax / 127.0f : 0.f;
  int* out = (int*)(Xq + (size_t)row * K_DIM);
#define PACK(V, IDX)                                                           \
  {                                                                            \
    int c0 = __float2int_rn(V[0] * inv), c1 = __float2int_rn(V[1] * inv);      \
    int c2 = __float2int_rn(V[2] * inv), c3 = __float2int_rn(V[3] * inv);      \
    out[IDX] = (c0 & 255) | ((c1 & 255) << 8) | ((c2 & 255) << 16) |           \
               ((c3 & 255) << 24);                                             \
  }
  PACK(v0, t) PACK(v1, t + 256) PACK(v2, t + 512) PACK(v3, t + 768)
#undef PACK
}

// ------- 256x256 i8 GEMM: BK=64 dbuf-2, 1 barrier + 1 vmcnt per K=64 ----------
// out[r][c] = gamma * xscale[r] * sum_k Wq[c][k] * Xq[r][k]  (exact i32 dot)
// 512 threads = 8 waves (2Mx4N), wave output 128x64 = 8x4 frags of
// mfma_i32_16x16x64_i8 (K=64 per instruction -> 32 MFMA/wave/tile).
// LDS: [2][256][64] i8 per matrix = 16KB/slot, A+B = 64KiB total.
// Tile p (slot s=p&1): stage tile p+1 -> s^1 (4 gload_lds); issue 12
// ds_read_b128 (b0-3, a0-3, a4-7; SB0-pinned groups); lgkm(4) -> 16 MFMA
// (a0-3 x b); lgkm(0) -> 16 MFMA (a4-7 x b); vmcnt(0); BAR.
// WAR audit: all reads of slot s^1 complete (lgkm(0) gates last MFMA block)
// before tile p-1's end-BAR; stage into s^1 issues after it. Stage lands
// within the ~2400cy tile body before VMC0.
// Swizzle (both-sides, rule 21): LDS[row][c16B] = global[row][c^((row>>1)&3)];
// staging permutes the GLOBAL chunk (LDS dest linear); reads fold the same
// XOR into the base (row bits[2:1] == lr bits[2:1] for every fragment row).
// Bank audit: 16 lanes x 4 banks = 64 accesses over 32 banks = 2-way = free.
__global__ __launch_bounds__(512, 2)
void gemm256_i8(const signed char* __restrict__ A,
                const signed char* __restrict__ Bq,
                float* __restrict__ C,
                const float* __restrict__ gamma_p,
                const float* __restrict__ xscale, int M, int N) {
  __shared__ __align__(16) signed char Abuf[2][256][64];  // 32 KiB
  __shared__ __align__(16) signed char Bbuf[2][256][64];  // 32 KiB

  int ntN = N >> 8;
  int bid = blockIdx.x;
  int swz = (bid & 7) * (gridDim.x >> 3) + (bid >> 3);  // nwg % 8 == 0
  int tm = swz / ntN, tn = swz % ntN;

  int t = threadIdx.x;
  int lane = t & 63;
  int wid = t >> 6;
  int wr = wid >> 2, wc = wid & 3;   // 2 x 4 wave grid
  int lr = lane & 15;
  int sc0 = (lane >> 4) ^ ((lr >> 1) & 3);  // swizzled 16B k-chunk (0..3)

  const signed char* aG = A + (size_t)tm * 256 * K_DIM;
  const signed char* bG = Bq + (size_t)tn * 256 * K_DIM;

  // staging: thread t -> LDS chunk (row = t>>2 [+128], c = t&3);
  // global source chunk = c ^ ((row>>1)&3); (row+128)>>1 keeps bits[1:0].
  int srow = t >> 2;
  int schunk = (t & 3) ^ ((t >> 3) & 3);
  const signed char* aSg = aG + (size_t)srow * K_DIM + (schunk << 4);
  const signed char* bSg = bG + (size_t)srow * K_DIM + (schunk << 4);
  char* aSl = (char*)Abuf + t * 16;
  char* bSl = (char*)Bbuf + t * 16;

  const signed char* aRd = &Abuf[0][0][0] + (wr * 128 + lr) * 64 + sc0 * 16;
  const signed char* bRd = &Bbuf[0][0][0] + (wc * 64 + lr) * 64 + sc0 * 16;

  i32x4 acc[8][4];
#pragma unroll
  for (int m = 0; m < 8; ++m)
#pragma unroll
    for (int n = 0; n < 4; ++n) acc[m][n] = (i32x4)(0);

#define STAGE_A(jj, S)                                                         \
  { GLOAD_LDS16(aSg + (size_t)(jj) * 64, aSl + (S) * 16384);                   \
    GLOAD_LDS16(aSg + (size_t)(jj) * 64 + (size_t)128 * K_DIM,                 \
                aSl + (S) * 16384 + 8192); }
#define STAGE_B(jj, S)                                                         \
  { GLOAD_LDS16(bSg + (size_t)(jj) * 64, bSl + (S) * 16384);                   \
    GLOAD_LDS16(bSg + (size_t)(jj) * 64 + (size_t)128 * K_DIM,                 \
                bSl + (S) * 16384 + 8192); }
#define BAR() __builtin_amdgcn_s_barrier()
#define VMC0() asm volatile("s_waitcnt vmcnt(0)" ::: "memory")
#define LGKM(NN) asm volatile("s_waitcnt lgkmcnt(" #NN ")" ::: "memory")
#define SB0() __builtin_amdgcn_sched_barrier(0)

  // TILE(S: slot const, JSTG: tile to stage, DO_STG, DO_END)
#define TILE(S, JSTG, DO_STG, DO_END)                                          \
  {                                                                            \
    if (DO_STG) { STAGE_A(JSTG, (S) ^ 1); STAGE_B(JSTG, (S) ^ 1); }            \
    _Pragma("unroll") for (int n = 0; n < 4; ++n)                              \
      bfr[n] = *(const i32x4*)(bRd + (S) * 16384 + n * 1024);                  \
    _Pragma("unroll") for (int m = 0; m < 4; ++m)                              \
      at[m] = *(const i32x4*)(aRd + (S) * 16384 + m * 1024);                   \
    SB0();                                                                     \
    _Pragma("unroll") for (int m = 0; m < 4; ++m)                              \
      ab[m] = *(const i32x4*)(aRd + (S) * 16384 + 4096 + m * 1024);            \
    SB0();                                                                     \
    LGKM(4); SB0();                                                            \
    __builtin_amdgcn_s_setprio(1);                                             \
    _Pragma("unroll") for (int m = 0; m < 4; ++m)                              \
      _Pragma("unroll") for (int n = 0; n < 4; ++n)                            \
        acc[m][n] = __builtin_amdgcn_mfma_i32_16x16x64_i8(                     \
            at[m], bfr[n], acc[m][n], 0, 0, 0);                                \
    __builtin_amdgcn_s_setprio(0);                                             \
    LGKM(0); SB0();                                                            \
    __builtin_amdgcn_s_setprio(1);                                             \
    _Pragma("unroll") for (int m = 0; m < 4; ++m)                              \
      _Pragma("unroll") for (int n = 0; n < 4; ++n)                            \
        acc[4 + m][n] = __builtin_amdgcn_mfma_i32_16x16x64_i8(                 \
            ab[m], bfr[n], acc[4 + m][n], 0, 0, 0);                            \
    __builtin_amdgcn_s_setprio(0);                                             \
    if (DO_END) { VMC0(); BAR(); }                                             \
  }

  // prologue: stage tile 0 -> slot 0, drain, publish
  STAGE_A(0, 0); STAGE_B(0, 0);
  VMC0();
  BAR();

  i32x4 at[4], ab[4], bfr[4];
  // tiles 0..61 (31 x 2), then 62 (stage 63), then 63 (no stage)
  for (int i = 0; i < 31; ++i) {
    int p = i << 1;
    TILE(0, p + 1, 1, 1);
    TILE(1, p + 2, 1, 1);
  }
  TILE(0, 63, 1, 1);
  TILE(1, 0, 0, 0);

  float g = gamma_p[0];
  int crow = (lane >> 4) << 2;   // C/D: col = lane&15, row = (lane>>4)*4 + reg
  size_t row0 = (size_t)tm * 256 + wr * 128 + crow;
  int col0 = tn * 256 + wc * 64 + lr;
#pragma unroll
  for (int m = 0; m < 8; ++m) {
#pragma unroll
    for (int j = 0; j < 4; ++j) {
      size_t row = row0 + m * 16 + j;
      float sc = g * xscale[row];
      float* cp = C + row * (size_t)N + col0;
#pragma unroll
      for (int n = 0; n < 4; ++n) cp[n * 16] = (float)acc[m][n][j] * sc;
    }
  }
#undef STAGE_A
#undef STAGE_B
#undef BAR
#undef VMC0
#undef LGKM
#undef SB0
#undef TILE
}

// ---------------- naive fallback (only if ws too small / odd shapes) ----------
__global__ void naive_bitlinear(const float* __restrict__ X,
                                const float* __restrict__ W,
                                float* __restrict__ out,
                                const float* __restrict__ gamma_p, int M, int N) {
  int col = blockIdx.x * blockDim.x + threadIdx.x;
  int row = blockIdx.y;
  if (col >= N || row >= M) return;
  float g = gamma_p[0];
  float safe = (g == 0.f) ? 1.f : g;
  const float* x = X + (size_t)row * K_DIM;
  const float* w = W + (size_t)col * K_DIM;
  float s = 0.f;
  for (int k = 0; k < K_DIM; ++k) {
    float qv = fminf(fmaxf(rintf(w[k] / safe), -1.f), 1.f);
    s += x[k] * qv;
  }
  out[(size_t)row * N + col] = s * g;
}

extern "C" void kernel_launch(void* const* d_in, const int* in_sizes, int n_in,
                              void* d_out, int out_size, void* d_ws,
                              size_t ws_size, hipStream_t stream) {
  const float* x = (const float*)d_in[0];
  const float* w = (const float*)d_in[1];
  float* out = (float*)d_out;
  int xn = in_sizes[0];   // B*S*D_IN = 33554432
  int wn = in_sizes[1];   // D_OUT*D_IN = 16777216
  int M = xn / K_DIM;     // 8192
  int N = wn / K_DIM;     // 4096

  char* ws = (char*)d_ws;
  float* partials = (float*)ws;                        // 1024 floats
  float* gamma = (float*)(ws + 4096);                  // 1 float
  float* xscale = (float*)(ws + 8192);                 // M floats (32 KiB)
  signed char* Wq = (signed char*)(ws + 8192 + 32768); // N*K i8
  signed char* Xq = Wq + (size_t)wn;                   // M*K i8
  size_t need = 8192 + 32768 + (size_t)wn + (size_t)xn;

  absum_partial<<<1024, 256, 0, stream>>>(w, partials, wn);
  gamma_finalize<<<1, 256, 0, stream>>>(partials, gamma, 1.0f / (float)wn);

  if (ws_size >= need && (M & 255) == 0 && (N & 255) == 0) {
    quantize_w_i8<<<2048, 256, 0, stream>>>(w, Wq, gamma, wn);
    quant_x_i8<<<M, 256, 0, stream>>>(x, Xq, xscale);
    int nwg = (M >> 8) * (N >> 8);   // 32 * 16 = 512
    gemm256_i8<<<nwg, 512, 0, stream>>>(Xq, Wq, out, gamma, xscale, M, N);
  } else {
    dim3 grid((N + 255) / 256, M);
    naive_bitlinear<<<grid, 256, 0, stream>>>(x, w, out, gamma, M, N);
  }
}